// Round 2
// baseline (13074.698 us; speedup 1.0000x reference)
//
#include <hip/hip_runtime.h>
#include <math.h>

// ---------------------------------------------------------------------------
// ODENet forward, f32 throughout.
//   state: [256, 64, 15, 15]  (225 pixels/channel)
//   ODE: 8 fixed dopri5 steps, 6 f-evals each; f fused into one kernel/stage.
// ---------------------------------------------------------------------------

#define NSAMP 256
#define NCH   64
#define NPIX  225          // 15*15
#define NPAD  289          // 17*17
#define NSTATE (NCH*NPIX)  // 14400 elems per sample

// ======================= fused ODE stage kernel ============================
// block = one sample, 512 threads.
// LDS: sY [64*225] f32 (57.6KB) + sX padded [64*17*17] f32 (74KB) + sA/sB.

__device__ __forceinline__ void gn_stats512(const float* sY,
    const float* __restrict__ gamma, const float* __restrict__ beta,
    float* sA, float* sB, int tid)
{
  int g = tid >> 4, lane = tid & 15;       // 32 groups x 16 lanes
  const float* pg = sY + g*450;            // group = 2 consecutive channels
  float s = 0.f, q = 0.f;
  for (int j = lane; j < 450; j += 16) { float v = pg[j]; s += v; q = fmaf(v, v, q); }
#pragma unroll
  for (int m = 1; m < 16; m <<= 1) { s += __shfl_xor(s, m); q += __shfl_xor(q, m); }
  if (lane == 0) {
    float mu  = s * (1.f/450.f);
    float var = fmaf(-mu, mu, q * (1.f/450.f));
    float rs  = 1.f / sqrtf(var + 1e-5f);
    int c0 = g*2;
    float a0 = rs*gamma[c0], a1 = rs*gamma[c0+1];
    sA[c0]   = a0; sB[c0]   = fmaf(-mu, a0, beta[c0]);
    sA[c0+1] = a1; sB[c0+1] = fmaf(-mu, a1, beta[c0+1]);
  }
  __syncthreads();
}

__device__ __forceinline__ void fill_padded_relu512(const float* sY, float* sX,
    const float* sA, const float* sB, int tid)
{
  for (int e = tid; e < NCH*NPAD; e += 512) {
    int c   = e / NPAD;
    int rem = e - c*NPAD;
    int r   = rem / 17, col = rem - r*17;
    float v = 0.f;
    if (r >= 1 && r <= 15 && col >= 1 && col <= 15)
      v = fmaxf(0.f, fmaf(sA[c], sY[c*NPIX + (r-1)*15 + (col-1)], sB[c]));
    sX[e] = v;
  }
  __syncthreads();
}

// conv 3x3, pad 1, 64->64 real channels + constant-t channel folded as bias.
// wt layout: [ic=0..64][tap=0..8][oc=0..63], ic 0 is the t channel.
__device__ __forceinline__ void conv3x3_512(const float* sX, float* sY,
    const float* __restrict__ wt, const float* __restrict__ bias,
    float tval, int tid)
{
  int half = tid >> 8;                                   // 0/1: oc 0..31 / 32..63
  int hu   = __builtin_amdgcn_readfirstlane(half);       // wave-uniform -> s_loads
  int p    = tid & 255;
  bool act = p < NPIX;
  int pp   = act ? p : 0;
  int py = pp / 15, px = pp - (pp/15)*15;
  int pbase = py*17 + px;
  float acc[32];
#pragma unroll
  for (int i = 0; i < 32; ++i) acc[i] = 0.f;

  for (int ic = 0; ic < 64; ++ic) {
    const float* wrow = wt + (ic+1)*576 + hu*32;
    const float* xrow = sX + ic*NPAD + pbase;
#pragma unroll
    for (int dy = 0; dy < 3; ++dy)
#pragma unroll
    for (int dx = 0; dx < 3; ++dx) {
      float v = xrow[dy*17 + dx];
      const float* wv = wrow + (dy*3 + dx)*64;
#pragma unroll
      for (int i = 0; i < 32; ++i) acc[i] = fmaf(v, wv[i], acc[i]);
    }
  }
  // t channel: contributes t * w_t[tap] for taps that land inside the image
#pragma unroll
  for (int dy = 0; dy < 3; ++dy)
#pragma unroll
  for (int dx = 0; dx < 3; ++dx) {
    int r = py + dy, cc = px + dx;
    float tv = (r >= 1 && r <= 15 && cc >= 1 && cc <= 15) ? tval : 0.f;
    const float* wv = wt + (dy*3 + dx)*64 + hu*32;
#pragma unroll
    for (int i = 0; i < 32; ++i) acc[i] = fmaf(tv, wv[i], acc[i]);
  }
  if (act) {
    const float* bb = bias + hu*32;
#pragma unroll
    for (int i = 0; i < 32; ++i) sY[(hu*32 + i)*NPIX + p] = acc[i] + bb[i];
  }
}

__global__ __launch_bounds__(512)
void ode_stage(const float* y, float* ywr, int writeY,
    int nc,
    const float* __restrict__ kA, float cA,
    const float* __restrict__ kB, float cB,
    const float* __restrict__ kC, float cC,
    const float* __restrict__ kD, float cD,
    const float* __restrict__ kE, float cE,
    float tval,
    const float* __restrict__ wtf1, const float* __restrict__ fb1,
    const float* __restrict__ wtf2, const float* __restrict__ fb2,
    const float* __restrict__ g1, const float* __restrict__ b1,
    const float* __restrict__ g2, const float* __restrict__ b2,
    const float* __restrict__ g3, const float* __restrict__ b3,
    float* __restrict__ kout)
{
  __shared__ float sY[NSTATE];
  __shared__ float sX[NCH*NPAD];
  __shared__ float sA[64], sB[64];
  int tid = threadIdx.x;
  size_t base = (size_t)blockIdx.x * NSTATE;

  // P0: RK combine into LDS (and optionally persist new y)
  for (int e = tid; e < NSTATE; e += 512) {
    float v = y[base + e];
    if (nc > 0) v = fmaf(cA, kA[base + e], v);
    if (nc > 1) v = fmaf(cB, kB[base + e], v);
    if (nc > 2) v = fmaf(cC, kC[base + e], v);
    if (nc > 3) v = fmaf(cD, kD[base + e], v);
    if (nc > 4) v = fmaf(cE, kE[base + e], v);
    sY[e] = v;
    if (writeY) ywr[base + e] = v;
  }
  __syncthreads();

  gn_stats512(sY, g1, b1, sA, sB, tid);          // f_gn1
  fill_padded_relu512(sY, sX, sA, sB, tid);      // relu + pad
  conv3x3_512(sX, sY, wtf1, fb1, tval, tid);     // f_conv1 (+t)
  __syncthreads();
  gn_stats512(sY, g2, b2, sA, sB, tid);          // f_gn2
  fill_padded_relu512(sY, sX, sA, sB, tid);
  conv3x3_512(sX, sY, wtf2, fb2, tval, tid);     // f_conv2 (+t)
  __syncthreads();
  gn_stats512(sY, g3, b3, sA, sB, tid);          // f_gn3 (no relu)

  for (int e = tid; e < NSTATE; e += 512) {
    int c = e / NPIX;
    kout[base + e] = fmaf(sA[c], sY[e], sB[c]);
  }
}

// ============================ phase A ======================================

// weight re-layouts: [oc][ic][taps] -> [ic][tap][oc]
__global__ void transpose_weights(
    const float* __restrict__ w2, const float* __restrict__ w3,
    const float* __restrict__ wf1, const float* __restrict__ wf2,
    float* __restrict__ wt2, float* __restrict__ wt3,
    float* __restrict__ wtf1, float* __restrict__ wtf2)
{
  int i = blockIdx.x*256 + threadIdx.x;
  if (i < 64*16*64) {              // conv2/conv3: [64][16][64]
    int ic = i >> 10, rem = i & 1023, tap = rem >> 6, oc = rem & 63;
    wt2[i] = w2[(oc*64 + ic)*16 + tap];
    wt3[i] = w3[(oc*64 + ic)*16 + tap];
  }
  if (i < 65*9*64) {               // f convs: [65][9][64]
    int ic = i / 576, rem = i - ic*576, tap = rem >> 6, oc = rem & 63;
    wtf1[i] = wf1[(oc*65 + ic)*9 + tap];
    wtf2[i] = wf2[(oc*65 + ic)*9 + tap];
  }
}

// GN1 stats: block = (sample, group). conv1 (1 input channel) recomputed.
__global__ __launch_bounds__(256)
void gn1_stats_kernel(const float* __restrict__ x,
    const float* __restrict__ w1, const float* __restrict__ b1,
    const float* __restrict__ g1g, const float* __restrict__ g1b,
    float* __restrict__ gn1A, float* __restrict__ gn1B)
{
  __shared__ float sXin[4096];
  __shared__ float red[16];
  int s = blockIdx.x >> 5, g = blockIdx.x & 31;
  int tid = threadIdx.x;
  const float* xs = x + (size_t)s*4096;
  for (int e = tid; e < 4096; e += 256) sXin[e] = xs[e];
  __syncthreads();
  int c0 = 2*g;
  float sum = 0.f, sq = 0.f;
  for (int e = tid; e < 2*3844; e += 256) {
    int hi = (e >= 3844);
    int c  = c0 + hi;
    int qq = e - hi*3844;
    int oy = qq / 62, ox = qq - oy*62;
    float v = b1[c];
#pragma unroll
    for (int ky = 0; ky < 3; ++ky)
#pragma unroll
    for (int kx = 0; kx < 3; ++kx)
      v = fmaf(sXin[(oy+ky)*64 + ox+kx], w1[c*9 + ky*3 + kx], v);
    sum += v; sq = fmaf(v, v, sq);
  }
#pragma unroll
  for (int m = 1; m < 64; m <<= 1) { sum += __shfl_xor(sum, m); sq += __shfl_xor(sq, m); }
  int w = tid >> 6;
  if ((tid & 63) == 0) { red[w] = sum; red[8+w] = sq; }
  __syncthreads();
  if (tid == 0) {
    float S = red[0]+red[1]+red[2]+red[3];
    float Q = red[8]+red[9]+red[10]+red[11];
    float n = 2.f*3844.f;
    float mu = S/n, var = fmaf(-mu, mu, Q/n);
    float rs = 1.f / sqrtf(var + 1e-5f);
    float a0 = rs*g1g[c0], a1 = rs*g1g[c0+1];
    gn1A[s*64+c0]   = a0; gn1B[s*64+c0]   = fmaf(-mu, a0, g1b[c0]);
    gn1A[s*64+c0+1] = a1; gn1B[s*64+c0+1] = fmaf(-mu, a1, g1b[c0+1]);
  }
}

// conv2 4x4 s2 p1 (h1 recomputed on the fly), writes raw output + GN2 partial sums.
__global__ __launch_bounds__(256)
void conv2_kernel(const float* __restrict__ x,
    const float* __restrict__ w1, const float* __restrict__ b1c,
    const float* __restrict__ gn1A, const float* __restrict__ gn1B,
    const float* __restrict__ wt2, const float* __restrict__ b2c,
    float* __restrict__ h2raw, float* __restrict__ gsum, float* __restrict__ gsq)
{
  __shared__ float sXin[400];          // 20x20 x-patch
  __shared__ float sH[64*324];         // 64 x 18x18 h1 patch
  int tile = blockIdx.x, s = blockIdx.y;
  int r0 = (tile >> 2)*8, c0 = (tile & 3)*8;
  int tid = threadIdx.x;
  int by = 2*r0 - 1, bx = 2*c0 - 1;
  const float* xs = x + (size_t)s*4096;
  for (int e = tid; e < 400; e += 256) {
    int r = e/20, c = e - r*20;
    int iy = by + r, ix = bx + c;
    sXin[e] = (iy >= 0 && iy < 64 && ix >= 0 && ix < 64) ? xs[iy*64 + ix] : 0.f;
  }
  __syncthreads();
  const float* A  = gn1A + s*64;
  const float* Bb = gn1B + s*64;
  for (int e = tid; e < 64*324; e += 256) {
    int ic = e/324, rem = e - ic*324;
    int r = rem/18, c = rem - r*18;
    int iy = by + r, ix = bx + c;
    float v = 0.f;
    if (iy >= 0 && iy < 62 && ix >= 0 && ix < 62) {
      float raw = b1c[ic];
#pragma unroll
      for (int ky = 0; ky < 3; ++ky)
#pragma unroll
      for (int kx = 0; kx < 3; ++kx)
        raw = fmaf(sXin[(r+ky)*20 + c+kx], w1[ic*9 + ky*3 + kx], raw);
      v = fmaxf(0.f, fmaf(A[ic], raw, Bb[ic]));
    }
    sH[e] = v;
  }
  __syncthreads();
  int ocq = __builtin_amdgcn_readfirstlane(tid >> 6);   // wave-uniform
  int p = tid & 63, py = p >> 3, px = p & 7;
  float acc[16];
#pragma unroll
  for (int i = 0; i < 16; ++i) acc[i] = 0.f;
  int pb = (2*py)*18 + 2*px;
  for (int ic = 0; ic < 64; ++ic) {
    const float* xr = sH + ic*324 + pb;
    const float* wr = wt2 + ic*1024 + ocq*16;
#pragma unroll
    for (int ky = 0; ky < 4; ++ky)
#pragma unroll
    for (int kx = 0; kx < 4; ++kx) {
      float v = xr[ky*18 + kx];
      const float* wv = wr + (ky*4 + kx)*64;
#pragma unroll
      for (int i = 0; i < 16; ++i) acc[i] = fmaf(v, wv[i], acc[i]);
    }
  }
  int oy = r0 + py, ox = c0 + px;
  bool valid = (oy < 31) && (ox < 31);
  float pg[8], pq[8];
#pragma unroll
  for (int i = 0; i < 8; ++i) { pg[i] = 0.f; pq[i] = 0.f; }
#pragma unroll
  for (int i = 0; i < 16; ++i) {
    int oc = ocq*16 + i;
    float v = valid ? acc[i] + b2c[oc] : 0.f;
    if (valid) h2raw[(((size_t)s*64 + oc)*31 + oy)*31 + ox] = v;
    pg[i>>1] += v; pq[i>>1] = fmaf(v, v, pq[i>>1]);
  }
#pragma unroll
  for (int m = 1; m < 64; m <<= 1)
#pragma unroll
    for (int i = 0; i < 8; ++i) { pg[i] += __shfl_xor(pg[i], m); pq[i] += __shfl_xor(pq[i], m); }
  if ((tid & 63) == 0) {
#pragma unroll
    for (int i = 0; i < 8; ++i) {
      atomicAdd(&gsum[s*32 + ocq*8 + i], pg[i]);
      atomicAdd(&gsq [s*32 + ocq*8 + i], pq[i]);
    }
  }
}

__global__ void gn2_finalize(const float* __restrict__ gsum, const float* __restrict__ gsq,
    const float* __restrict__ g2g, const float* __restrict__ g2b,
    float* __restrict__ gn2A, float* __restrict__ gn2B)
{
  int i = blockIdx.x*256 + threadIdx.x;
  if (i >= 256*32) return;
  int s = i >> 5, g = i & 31;
  float n = 2.f*961.f;
  float mu = gsum[i]/n, var = fmaf(-mu, mu, gsq[i]/n);
  float rs = 1.f / sqrtf(var + 1e-5f);
  int c0 = 2*g;
  float a0 = rs*g2g[c0], a1 = rs*g2g[c0+1];
  gn2A[s*64+c0]   = a0; gn2B[s*64+c0]   = fmaf(-mu, a0, g2b[c0]);
  gn2A[s*64+c0+1] = a1; gn2B[s*64+c0+1] = fmaf(-mu, a1, g2b[c0+1]);
}

// conv3 4x4 s2 p1 (GN2+relu applied while staging), writes y0 [256,64,15,15]
__global__ __launch_bounds__(256)
void conv3_kernel(const float* __restrict__ h2raw,
    const float* __restrict__ gn2A, const float* __restrict__ gn2B,
    const float* __restrict__ wt3, const float* __restrict__ b3c,
    float* __restrict__ y)
{
  __shared__ float sH[64*324];
  int tile = blockIdx.x, s = blockIdx.y;
  int r0 = (tile >> 1)*8, c0 = (tile & 1)*8;
  int tid = threadIdx.x;
  int by = 2*r0 - 1, bx = 2*c0 - 1;
  const float* A  = gn2A + s*64;
  const float* Bb = gn2B + s*64;
  for (int e = tid; e < 64*324; e += 256) {
    int ic = e/324, rem = e - ic*324;
    int r = rem/18, c = rem - r*18;
    int iy = by + r, ix = bx + c;
    float v = 0.f;
    if (iy >= 0 && iy < 31 && ix >= 0 && ix < 31) {
      float raw = h2raw[(((size_t)s*64 + ic)*31 + iy)*31 + ix];
      v = fmaxf(0.f, fmaf(A[ic], raw, Bb[ic]));
    }
    sH[e] = v;
  }
  __syncthreads();
  int ocq = __builtin_amdgcn_readfirstlane(tid >> 6);
  int p = tid & 63, py = p >> 3, px = p & 7;
  float acc[16];
#pragma unroll
  for (int i = 0; i < 16; ++i) acc[i] = 0.f;
  int pb = (2*py)*18 + 2*px;
  for (int ic = 0; ic < 64; ++ic) {
    const float* xr = sH + ic*324 + pb;
    const float* wr = wt3 + ic*1024 + ocq*16;
#pragma unroll
    for (int t = 0; t < 16; ++t) {
      float v = xr[(t>>2)*18 + (t&3)];
      const float* wv = wr + t*64;
#pragma unroll
      for (int i = 0; i < 16; ++i) acc[i] = fmaf(v, wv[i], acc[i]);
    }
  }
  int oy = r0 + py, ox = c0 + px;
  if (oy < 15 && ox < 15) {
#pragma unroll
    for (int i = 0; i < 16; ++i) {
      int oc = ocq*16 + i;
      y[((size_t)s*64 + oc)*NPIX + oy*15 + ox] = acc[i] + b3c[oc];
    }
  }
}

// ============================ head =========================================
__global__ __launch_bounds__(256)
void head_kernel(const float* __restrict__ y,
    const float* __restrict__ k1, const float* __restrict__ k3,
    const float* __restrict__ k4, const float* __restrict__ k5,
    const float* __restrict__ k6,
    float c1, float c3, float c4, float c5, float c6,
    const float* __restrict__ og, const float* __restrict__ ob,
    const float* __restrict__ fcw, const float* __restrict__ fcb,
    float* __restrict__ out)
{
  __shared__ float sY[NSTATE];
  __shared__ float sA[64], sB[64], sM[64];
  int tid = threadIdx.x, s = blockIdx.x;
  size_t base = (size_t)s * NSTATE;
  for (int e = tid; e < NSTATE; e += 256) {
    float v = y[base + e];
    v = fmaf(c1, k1[base + e], v);
    v = fmaf(c3, k3[base + e], v);
    v = fmaf(c4, k4[base + e], v);
    v = fmaf(c5, k5[base + e], v);
    v = fmaf(c6, k6[base + e], v);
    sY[e] = v;
  }
  __syncthreads();
  {
    int g = tid >> 3, lane = tid & 7;     // 32 groups x 8 lanes
    const float* pg = sY + g*450;
    float ssum = 0.f, q = 0.f;
    for (int j = lane; j < 450; j += 8) { float v = pg[j]; ssum += v; q = fmaf(v, v, q); }
#pragma unroll
    for (int m = 1; m < 8; m <<= 1) { ssum += __shfl_xor(ssum, m); q += __shfl_xor(q, m); }
    if (lane == 0) {
      float mu = ssum*(1.f/450.f);
      float var = fmaf(-mu, mu, q*(1.f/450.f));
      float rs = 1.f / sqrtf(var + 1e-5f);
      int c0 = 2*g;
      float a0 = rs*og[c0], a1 = rs*og[c0+1];
      sA[c0]   = a0; sB[c0]   = fmaf(-mu, a0, ob[c0]);
      sA[c0+1] = a1; sB[c0+1] = fmaf(-mu, a1, ob[c0+1]);
    }
    __syncthreads();
  }
  {
    int c = tid >> 2, l = tid & 3;        // 64 channels x 4 lanes
    const float* pc = sY + c*NPIX;
    float m = 0.f;
    for (int j = l; j < NPIX; j += 4) m += fmaxf(0.f, fmaf(sA[c], pc[j], sB[c]));
#pragma unroll
    for (int mm = 1; mm < 4; mm <<= 1) m += __shfl_xor(m, mm);
    if (l == 0) sM[c] = m * (1.f/225.f);
  }
  __syncthreads();
  if (tid < 10) {
    float v = fcb[tid];
    const float* wr = fcw + tid*64;
    for (int c = 0; c < 64; ++c) v = fmaf(sM[c], wr[c], v);
    out[s*10 + tid] = v;
  }
}

// ============================ host =========================================
extern "C" void kernel_launch(void* const* d_in, const int* in_sizes, int n_in,
                              void* d_out, int out_size, void* d_ws, size_t ws_size,
                              hipStream_t stream)
{
  const float* x    = (const float*)d_in[0];
  const float* w1   = (const float*)d_in[1];
  const float* b1   = (const float*)d_in[2];
  const float* g1g  = (const float*)d_in[3];
  const float* g1b  = (const float*)d_in[4];
  const float* w2   = (const float*)d_in[5];
  const float* b2   = (const float*)d_in[6];
  const float* g2g  = (const float*)d_in[7];
  const float* g2b  = (const float*)d_in[8];
  const float* w3   = (const float*)d_in[9];
  const float* b3   = (const float*)d_in[10];
  const float* fg1g = (const float*)d_in[11];
  const float* fg1b = (const float*)d_in[12];
  const float* fw1  = (const float*)d_in[13];
  const float* fb1  = (const float*)d_in[14];
  const float* fg2g = (const float*)d_in[15];
  const float* fg2b = (const float*)d_in[16];
  const float* fw2  = (const float*)d_in[17];
  const float* fb2  = (const float*)d_in[18];
  const float* fg3g = (const float*)d_in[19];
  const float* fg3b = (const float*)d_in[20];
  const float* ogg  = (const float*)d_in[21];
  const float* ogb  = (const float*)d_in[22];
  const float* fcw  = (const float*)d_in[23];
  const float* fcb  = (const float*)d_in[24];
  float* out = (float*)d_out;

  char* ws = (char*)d_ws;
  size_t off = 0;
  auto alloc = [&](size_t bytes) -> void* {
    void* p = ws + off; off += (bytes + 255) & ~(size_t)255; return p;
  };
  const size_t NST = (size_t)NSAMP * NSTATE;        // 3,686,400
  float* y = (float*)alloc(NST * 4);
  char* kbase = ws + off;
  float* k[6];
  for (int i = 0; i < 6; ++i) k[i] = (float*)alloc(NST * 4);
  float* h2raw = (float*)kbase;                     // overlap: dead before k's used
  float* gn1A = (float*)alloc(256*64*4);
  float* gn1B = (float*)alloc(256*64*4);
  float* gn2A = (float*)alloc(256*64*4);
  float* gn2B = (float*)alloc(256*64*4);
  float* gsum = (float*)alloc(256*32*4);
  float* gsq  = (float*)alloc(256*32*4);
  float* wt2  = (float*)alloc(64*16*64*4);
  float* wt3  = (float*)alloc(64*16*64*4);
  float* wtf1 = (float*)alloc(65*9*64*4);
  float* wtf2 = (float*)alloc(65*9*64*4);
  if (off > ws_size) return;   // clean failure if scratch too small

  hipMemsetAsync(gsum, 0, 256*32*4, stream);
  hipMemsetAsync(gsq,  0, 256*32*4, stream);

  transpose_weights<<<256, 256, 0, stream>>>(w2, w3, fw1, fw2, wt2, wt3, wtf1, wtf2);
  gn1_stats_kernel<<<256*32, 256, 0, stream>>>(x, w1, b1, g1g, g1b, gn1A, gn1B);
  conv2_kernel<<<dim3(16, 256), 256, 0, stream>>>(x, w1, b1, gn1A, gn1B, wt2, b2,
                                                  h2raw, gsum, gsq);
  gn2_finalize<<<32, 256, 0, stream>>>(gsum, gsq, g2g, g2b, gn2A, gn2B);
  conv3_kernel<<<dim3(4, 256), 256, 0, stream>>>(h2raw, gn2A, gn2B, wt3, b3, y);

  const double hs = 1.0/8.0;
  const double A21 = 1.0/5, A31 = 3./40, A32 = 9./40,
      A41 = 44./45, A42 = -56./15, A43 = 32./9,
      A51 = 19372./6561, A52 = -25360./2187, A53 = 64448./6561, A54 = -212./729,
      A61 = 9017./3168, A62 = -355./33, A63 = 46732./5247, A64 = 49./176, A65 = -5103./18656,
      B1 = 35./384, B3 = 500./1113, B4 = 125./192, B5 = -2187./6784, B6 = 11./84;

  auto stage = [&](int writeY, int nc,
                   const float* kA, double cA, const float* kB, double cB,
                   const float* kC, double cC, const float* kD, double cD,
                   const float* kE, double cE, double t, float* kout) {
    ode_stage<<<256, 512, 0, stream>>>(y, y, writeY, nc,
        kA, (float)(hs*cA), kB, (float)(hs*cB), kC, (float)(hs*cC),
        kD, (float)(hs*cD), kE, (float)(hs*cE), (float)t,
        wtf1, fb1, wtf2, fb2, fg1g, fg1b, fg2g, fg2b, fg3g, fg3b, kout);
  };

  for (int i = 0; i < 8; ++i) {
    double t0 = i * hs;
    if (i == 0) stage(0, 0, y,0, y,0, y,0, y,0, y,0, t0, k[0]);
    else        stage(1, 5, k[0],B1, k[2],B3, k[3],B4, k[4],B5, k[5],B6, t0, k[0]);
    stage(0, 1, k[0],A21, y,0,      y,0,      y,0,      y,0,      t0 + hs*(1.0/5), k[1]);
    stage(0, 2, k[0],A31, k[1],A32, y,0,      y,0,      y,0,      t0 + hs*0.3,     k[2]);
    stage(0, 3, k[0],A41, k[1],A42, k[2],A43, y,0,      y,0,      t0 + hs*0.8,     k[3]);
    stage(0, 4, k[0],A51, k[1],A52, k[2],A53, k[3],A54, y,0,      t0 + hs*(8.0/9), k[4]);
    stage(0, 5, k[0],A61, k[1],A62, k[2],A63, k[3],A64, k[4],A65, t0 + hs,         k[5]);
  }
  head_kernel<<<256, 256, 0, stream>>>(y, k[0], k[2], k[3], k[4], k[5],
      (float)(hs*B1), (float)(hs*B3), (float)(hs*B4), (float)(hs*B5), (float)(hs*B6),
      ogg, ogb, fcw, fcb, out);
}

// Round 8
// 3785.179 us; speedup vs baseline: 3.4542x; 3.4542x over previous
//
#include <hip/hip_runtime.h>
#include <math.h>

// ---------------------------------------------------------------------------
// ODENet forward. ODE stage uses bf16 MFMA implicit-GEMM; state stays f32.
//   state: [256, 225 pix, 64 ch]  (channel-last, f32)
// ---------------------------------------------------------------------------

#define NSAMP 256
#define NCH   64
#define NPIX  225           // 15*15
#define NSTATE (NCH*NPIX)   // 14400 per sample
#define CSX   72            // ushort stride of sXc rows (bank-stride 4)
#define CSY   68            // f32 stride of sYc rows (bank-stride 4)
#define XROWS 306           // 18*17 padded rows (covers ghost pixels 225..239)

typedef __attribute__((ext_vector_type(8))) short  sh8;
typedef __attribute__((ext_vector_type(4))) float  f32x4;
typedef __attribute__((ext_vector_type(2))) float  f32x2;

__device__ __forceinline__ unsigned short f2bf(float f) {
  unsigned u = __float_as_uint(f);
  u += 0x7FFFu + ((u >> 16) & 1u);        // RNE
  return (unsigned short)(u >> 16);
}

// ======================= fused ODE stage (MFMA) ============================
// block = one sample, 512 threads = 8 waves.
// wave w: och = w&1 (oc 32*och..+32, held as 2 oc-tiles of weights in regs),
//         pg = w>>1 (pixel-tile group: 4,4,4,3 tiles of 16 pixels).

__device__ __forceinline__ void gn_stats_cl(const float* sYc,
    const float* __restrict__ gamma, const float* __restrict__ beta,
    float* sA, float* sB, int tid)
{
  int g = tid >> 4, lane = tid & 15, c0 = g*2;   // 32 groups x 16 lanes
  float s = 0.f, q = 0.f;
  for (int pix = lane; pix < NPIX; pix += 16) {
    f32x2 v = *(const f32x2*)&sYc[pix*CSY + c0];
    s += v.x + v.y;
    q = fmaf(v.x, v.x, fmaf(v.y, v.y, q));
  }
#pragma unroll
  for (int m = 1; m < 16; m <<= 1) { s += __shfl_xor(s, m); q += __shfl_xor(q, m); }
  if (lane == 0) {
    float mu  = s * (1.f/450.f);
    float var = fmaf(-mu, mu, q * (1.f/450.f));
    float rs  = 1.f / sqrtf(var + 1e-5f);
    float a0 = rs*gamma[c0], a1 = rs*gamma[c0+1];
    sA[c0]   = a0; sB[c0]   = fmaf(-mu, a0, beta[c0]);
    sA[c0+1] = a1; sB[c0+1] = fmaf(-mu, a1, beta[c0+1]);
  }
  __syncthreads();
}

// relu(GN(x)) -> padded channel-last bf16
__device__ __forceinline__ void build_sxc(const float* sYc, unsigned short* sXc,
    const float* sA, const float* sB, int tid)
{
  for (int e = tid; e < XROWS*32; e += 512) {
    int prow = e >> 5, cp = e & 31, c0 = cp*2;
    int r = prow/17, cc = prow - r*17;
    unsigned pack = 0u;
    if (r >= 1 && r <= 15 && cc >= 1 && cc <= 15) {
      int pix = (r-1)*15 + (cc-1);
      f32x2 v = *(const f32x2*)&sYc[pix*CSY + c0];
      float a0 = fmaxf(0.f, fmaf(sA[c0],   v.x, sB[c0]));
      float a1 = fmaxf(0.f, fmaf(sA[c0+1], v.y, sB[c0+1]));
      pack = (unsigned)f2bf(a0) | ((unsigned)f2bf(a1) << 16);
    }
    *(unsigned*)&sXc[prow*CSX + c0] = pack;
  }
  __syncthreads();
}

// one 64->64 3x3 conv via mfma_f32_16x16x32_bf16; t-channel via class table.
__device__ __forceinline__ void conv_mfma(const unsigned short* sXc, float* sYc,
    const sh8* w0, const sh8* w1r,
    const float* __restrict__ bias, const float* __restrict__ ts, float tval,
    int och, int pg, int l)
{
  int lr = l & 15, lg = l >> 4;
  int nt = (pg < 3) ? 4 : 3;
  for (int ti = 0; ti < nt; ++ti) {
    int pt = pg*4 + ti;
    int pix = pt*16 + lr;                 // 0..239 (225..239 = ghost)
    int py = pix/15, px = pix - py*15;
    const unsigned short* bp = sXc + ((py*17 + px)*CSX + lg*8);
    f32x4 a0 = {0.f,0.f,0.f,0.f}, a1 = {0.f,0.f,0.f,0.f};
#pragma unroll
    for (int kb = 0; kb < 18; ++kb) {
      int tap = kb >> 1;
      int off = ((tap/3)*17 + (tap%3))*CSX + (kb & 1)*32;   // compile-time
      sh8 b = *(const sh8*)(bp + off);
      a0 = __builtin_amdgcn_mfma_f32_16x16x32_bf16(w0[kb],  b, a0, 0, 0, 0);
      a1 = __builtin_amdgcn_mfma_f32_16x16x32_bf16(w1r[kb], b, a1, 0, 0, 0);
    }
    if (pix < NPIX) {
      int cy = (py == 0) ? 0 : ((py == 14) ? 2 : 1);
      int cx = (px == 0) ? 0 : ((px == 14) ? 2 : 1);
      const float* tsp = ts + (cy*3 + cx)*64;
      int ocb = och*32 + lg*4;
      f32x4 o0, o1;
#pragma unroll
      for (int r = 0; r < 4; ++r) {
        o0[r] = a0[r] + bias[ocb+r]    + tval*tsp[ocb+r];
        o1[r] = a1[r] + bias[ocb+16+r] + tval*tsp[ocb+16+r];
      }
      *(f32x4*)&sYc[pix*CSY + ocb]      = o0;
      *(f32x4*)&sYc[pix*CSY + ocb + 16] = o1;
    }
  }
}

__global__ __launch_bounds__(512, 2)
void ode_stage(const float* y, float* ywr, int writeY, int nc,
    const float* __restrict__ kA, float cA,
    const float* __restrict__ kB, float cB,
    const float* __restrict__ kC, float cC,
    const float* __restrict__ kD, float cD,
    const float* __restrict__ kE, float cE,
    float tval,
    const unsigned short* __restrict__ wb1, const float* __restrict__ bias1,
    const float* __restrict__ ts1,
    const unsigned short* __restrict__ wb2, const float* __restrict__ bias2,
    const float* __restrict__ ts2,
    const float* __restrict__ g1, const float* __restrict__ b1,
    const float* __restrict__ g2, const float* __restrict__ b2,
    const float* __restrict__ g3, const float* __restrict__ b3,
    float* __restrict__ kout)
{
  __shared__ float         sYc[NPIX*CSY];     // 61.2 KB
  __shared__ unsigned short sXc[XROWS*CSX];   // 44.1 KB
  __shared__ float sA[64], sB[64];

  int tid = threadIdx.x, l = tid & 63, w = tid >> 6;
  int och = w & 1, pg = w >> 1;
  int lr = l & 15, lg = l >> 4;
  size_t base = (size_t)blockIdx.x * NSTATE;

  // preload conv1 weights into regs: 2 oc-tiles x 18 K-steps (144 VGPR)
  sh8 w0[18], w1r[18];
  {
    const unsigned short* p0 = wb1 + ((och*32 + lr)*64 + lg*8);
    const unsigned short* p1 = p0 + 16*64;
#pragma unroll
    for (int kb = 0; kb < 18; ++kb) {
      int off = (kb >> 1)*4096 + (kb & 1)*32;
      w0[kb]  = *(const sh8*)(p0 + off);
      w1r[kb] = *(const sh8*)(p1 + off);
    }
  }

  // RK combine (global [pix][ch] f32) -> sYc; optionally persist new y
  for (int e = tid; e < 3600; e += 512) {
    size_t g = base + (size_t)e*4;
    f32x4 v = *(const f32x4*)(y + g);
    if (nc > 0) { f32x4 t = *(const f32x4*)(kA + g); v += cA*t; }
    if (nc > 1) { f32x4 t = *(const f32x4*)(kB + g); v += cB*t; }
    if (nc > 2) { f32x4 t = *(const f32x4*)(kC + g); v += cC*t; }
    if (nc > 3) { f32x4 t = *(const f32x4*)(kD + g); v += cD*t; }
    if (nc > 4) { f32x4 t = *(const f32x4*)(kE + g); v += cE*t; }
    if (writeY) *(f32x4*)(ywr + g) = v;
    int pix = e >> 4, q = e & 15;
    *(f32x4*)&sYc[pix*CSY + q*4] = v;
  }
  __syncthreads();

  gn_stats_cl(sYc, g1, b1, sA, sB, tid);                 // f_gn1
  build_sxc(sYc, sXc, sA, sB, tid);                      // relu + pad -> bf16
  conv_mfma(sXc, sYc, w0, w1r, bias1, ts1, tval, och, pg, l);   // f_conv1

  { // preload conv2 weights (register-only; no LDS hazard)
    const unsigned short* p0 = wb2 + ((och*32 + lr)*64 + lg*8);
    const unsigned short* p1 = p0 + 16*64;
#pragma unroll
    for (int kb = 0; kb < 18; ++kb) {
      int off = (kb >> 1)*4096 + (kb & 1)*32;
      w0[kb]  = *(const sh8*)(p0 + off);
      w1r[kb] = *(const sh8*)(p1 + off);
    }
  }
  __syncthreads();

  gn_stats_cl(sYc, g2, b2, sA, sB, tid);                 // f_gn2
  build_sxc(sYc, sXc, sA, sB, tid);
  conv_mfma(sXc, sYc, w0, w1r, bias2, ts2, tval, och, pg, l);   // f_conv2
  __syncthreads();

  gn_stats_cl(sYc, g3, b3, sA, sB, tid);                 // f_gn3 (no relu)

  for (int e = tid; e < 3600; e += 512) {
    int pix = e >> 4, q = e & 15, c0 = q*4;
    f32x4 v = *(const f32x4*)&sYc[pix*CSY + c0];
    f32x4 o;
#pragma unroll
    for (int r = 0; r < 4; ++r) o[r] = fmaf(sA[c0+r], v[r], sB[c0+r]);
    *(f32x4*)(kout + base + (size_t)e*4) = o;
  }
}

// ============================ weight prep ==================================
// wt2/wt3: [ic][tap][oc] f32 (phase-A convs).
// wtb1/wtb2: [tap][oc][ch] bf16 (ODE convs, real channels = ic 1..64).
// ts1/ts2: [class 3x3][oc] f32 = sum of t-channel taps valid per boundary class.
__global__ void transpose_weights(
    const float* __restrict__ w2, const float* __restrict__ w3,
    const float* __restrict__ wf1, const float* __restrict__ wf2,
    float* __restrict__ wt2, float* __restrict__ wt3,
    unsigned short* __restrict__ wtb1, unsigned short* __restrict__ wtb2,
    float* __restrict__ ts1, float* __restrict__ ts2)
{
  int i = blockIdx.x*256 + threadIdx.x;
  if (i < 64*16*64) {              // conv2/conv3: [64][16][64]
    int ic = i >> 10, rem = i & 1023, tap = rem >> 6, oc = rem & 63;
    wt2[i] = w2[(oc*64 + ic)*16 + tap];
    wt3[i] = w3[(oc*64 + ic)*16 + tap];
  }
  if (i < 9*64*64) {               // [tap][oc][ch]
    int tap = i >> 12, oc = (i >> 6) & 63, ch = i & 63;
    wtb1[i] = f2bf(wf1[(oc*65 + ch + 1)*9 + tap]);
    wtb2[i] = f2bf(wf2[(oc*65 + ch + 1)*9 + tap]);
  }
  if (i < 576) {                   // t-channel class sums
    int cls = i >> 6, oc = i & 63;
    int cy = cls/3, cx = cls - cy*3;
    int dy0 = (cy == 0) ? 1 : 0, dy1 = (cy == 2) ? 1 : 2;
    int dx0 = (cx == 0) ? 1 : 0, dx1 = (cx == 2) ? 1 : 2;
    float s1 = 0.f, s2 = 0.f;
    for (int dy = dy0; dy <= dy1; ++dy)
      for (int dx = dx0; dx <= dx1; ++dx) {
        s1 += wf1[(oc*65 + 0)*9 + dy*3 + dx];
        s2 += wf2[(oc*65 + 0)*9 + dy*3 + dx];
      }
    ts1[i] = s1; ts2[i] = s2;
  }
}

// ============================ phase A ======================================

__global__ __launch_bounds__(256)
void gn1_stats_kernel(const float* __restrict__ x,
    const float* __restrict__ w1, const float* __restrict__ b1,
    const float* __restrict__ g1g, const float* __restrict__ g1b,
    float* __restrict__ gn1A, float* __restrict__ gn1B)
{
  __shared__ float sXin[4096];
  __shared__ float red[16];
  int s = blockIdx.x >> 5, g = blockIdx.x & 31;
  int tid = threadIdx.x;
  const float* xs = x + (size_t)s*4096;
  for (int e = tid; e < 4096; e += 256) sXin[e] = xs[e];
  __syncthreads();
  int c0 = 2*g;
  float sum = 0.f, sq = 0.f;
  for (int e = tid; e < 2*3844; e += 256) {
    int hi = (e >= 3844);
    int c  = c0 + hi;
    int qq = e - hi*3844;
    int oy = qq / 62, ox = qq - oy*62;
    float v = b1[c];
#pragma unroll
    for (int ky = 0; ky < 3; ++ky)
#pragma unroll
    for (int kx = 0; kx < 3; ++kx)
      v = fmaf(sXin[(oy+ky)*64 + ox+kx], w1[c*9 + ky*3 + kx], v);
    sum += v; sq = fmaf(v, v, sq);
  }
#pragma unroll
  for (int m = 1; m < 64; m <<= 1) { sum += __shfl_xor(sum, m); sq += __shfl_xor(sq, m); }
  int w = tid >> 6;
  if ((tid & 63) == 0) { red[w] = sum; red[8+w] = sq; }
  __syncthreads();
  if (tid == 0) {
    float S = red[0]+red[1]+red[2]+red[3];
    float Q = red[8]+red[9]+red[10]+red[11];
    float n = 2.f*3844.f;
    float mu = S/n, var = fmaf(-mu, mu, Q/n);
    float rs = 1.f / sqrtf(var + 1e-5f);
    float a0 = rs*g1g[c0], a1 = rs*g1g[c0+1];
    gn1A[s*64+c0]   = a0; gn1B[s*64+c0]   = fmaf(-mu, a0, g1b[c0]);
    gn1A[s*64+c0+1] = a1; gn1B[s*64+c0+1] = fmaf(-mu, a1, g1b[c0+1]);
  }
}

__global__ __launch_bounds__(256)
void conv2_kernel(const float* __restrict__ x,
    const float* __restrict__ w1, const float* __restrict__ b1c,
    const float* __restrict__ gn1A, const float* __restrict__ gn1B,
    const float* __restrict__ wt2, const float* __restrict__ b2c,
    float* __restrict__ h2raw, float* __restrict__ gsum, float* __restrict__ gsq)
{
  __shared__ float sXin[400];          // 20x20 x-patch
  __shared__ float sH[64*324];         // 64 x 18x18 h1 patch
  int tile = blockIdx.x, s = blockIdx.y;
  int r0 = (tile >> 2)*8, c0 = (tile & 3)*8;
  int tid = threadIdx.x;
  int by = 2*r0 - 1, bx = 2*c0 - 1;
  const float* xs = x + (size_t)s*4096;
  for (int e = tid; e < 400; e += 256) {
    int r = e/20, c = e - r*20;
    int iy = by + r, ix = bx + c;
    sXin[e] = (iy >= 0 && iy < 64 && ix >= 0 && ix < 64) ? xs[iy*64 + ix] : 0.f;
  }
  __syncthreads();
  const float* A  = gn1A + s*64;
  const float* Bb = gn1B + s*64;
  for (int e = tid; e < 64*324; e += 256) {
    int ic = e/324, rem = e - ic*324;
    int r = rem/18, c = rem - r*18;
    int iy = by + r, ix = bx + c;
    float v = 0.f;
    if (iy >= 0 && iy < 62 && ix >= 0 && ix < 62) {
      float raw = b1c[ic];
#pragma unroll
      for (int ky = 0; ky < 3; ++ky)
#pragma unroll
      for (int kx = 0; kx < 3; ++kx)
        raw = fmaf(sXin[(r+ky)*20 + c+kx], w1[ic*9 + ky*3 + kx], raw);
      v = fmaxf(0.f, fmaf(A[ic], raw, Bb[ic]));
    }
    sH[e] = v;
  }
  __syncthreads();
  int ocq = __builtin_amdgcn_readfirstlane(tid >> 6);
  int p = tid & 63, py = p >> 3, px = p & 7;
  float acc[16];
#pragma unroll
  for (int i = 0; i < 16; ++i) acc[i] = 0.f;
  int pb = (2*py)*18 + 2*px;
  for (int ic = 0; ic < 64; ++ic) {
    const float* xr = sH + ic*324 + pb;
    const float* wr = wt2 + ic*1024 + ocq*16;
#pragma unroll
    for (int ky = 0; ky < 4; ++ky)
#pragma unroll
    for (int kx = 0; kx < 4; ++kx) {
      float v = xr[ky*18 + kx];
      const float* wv = wr + (ky*4 + kx)*64;
#pragma unroll
      for (int i = 0; i < 16; ++i) acc[i] = fmaf(v, wv[i], acc[i]);
    }
  }
  int oy = r0 + py, ox = c0 + px;
  bool valid = (oy < 31) && (ox < 31);
  float pg[8], pq[8];
#pragma unroll
  for (int i = 0; i < 8; ++i) { pg[i] = 0.f; pq[i] = 0.f; }
#pragma unroll
  for (int i = 0; i < 16; ++i) {
    int oc = ocq*16 + i;
    float v = valid ? acc[i] + b2c[oc] : 0.f;
    if (valid) h2raw[(((size_t)s*64 + oc)*31 + oy)*31 + ox] = v;
    pg[i>>1] += v; pq[i>>1] = fmaf(v, v, pq[i>>1]);
  }
#pragma unroll
  for (int m = 1; m < 64; m <<= 1)
#pragma unroll
    for (int i = 0; i < 8; ++i) { pg[i] += __shfl_xor(pg[i], m); pq[i] += __shfl_xor(pq[i], m); }
  if ((tid & 63) == 0) {
#pragma unroll
    for (int i = 0; i < 8; ++i) {
      atomicAdd(&gsum[s*32 + ocq*8 + i], pg[i]);
      atomicAdd(&gsq [s*32 + ocq*8 + i], pq[i]);
    }
  }
}

__global__ void gn2_finalize(const float* __restrict__ gsum, const float* __restrict__ gsq,
    const float* __restrict__ g2g, const float* __restrict__ g2b,
    float* __restrict__ gn2A, float* __restrict__ gn2B)
{
  int i = blockIdx.x*256 + threadIdx.x;
  if (i >= 256*32) return;
  int s = i >> 5, g = i & 31;
  float n = 2.f*961.f;
  float mu = gsum[i]/n, var = fmaf(-mu, mu, gsq[i]/n);
  float rs = 1.f / sqrtf(var + 1e-5f);
  int c0 = 2*g;
  float a0 = rs*g2g[c0], a1 = rs*g2g[c0+1];
  gn2A[s*64+c0]   = a0; gn2B[s*64+c0]   = fmaf(-mu, a0, g2b[c0]);
  gn2A[s*64+c0+1] = a1; gn2B[s*64+c0+1] = fmaf(-mu, a1, g2b[c0+1]);
}

// conv3 4x4 s2 p1; writes y0 channel-last [s][pix][ch]
__global__ __launch_bounds__(256)
void conv3_kernel(const float* __restrict__ h2raw,
    const float* __restrict__ gn2A, const float* __restrict__ gn2B,
    const float* __restrict__ wt3, const float* __restrict__ b3c,
    float* __restrict__ y)
{
  __shared__ float sH[64*324];
  int tile = blockIdx.x, s = blockIdx.y;
  int r0 = (tile >> 1)*8, c0 = (tile & 1)*8;
  int tid = threadIdx.x;
  int by = 2*r0 - 1, bx = 2*c0 - 1;
  const float* A  = gn2A + s*64;
  const float* Bb = gn2B + s*64;
  for (int e = tid; e < 64*324; e += 256) {
    int ic = e/324, rem = e - ic*324;
    int r = rem/18, c = rem - r*18;
    int iy = by + r, ix = bx + c;
    float v = 0.f;
    if (iy >= 0 && iy < 31 && ix >= 0 && ix < 31) {
      float raw = h2raw[(((size_t)s*64 + ic)*31 + iy)*31 + ix];
      v = fmaxf(0.f, fmaf(A[ic], raw, Bb[ic]));
    }
    sH[e] = v;
  }
  __syncthreads();
  int ocq = __builtin_amdgcn_readfirstlane(tid >> 6);
  int p = tid & 63, py = p >> 3, px = p & 7;
  float acc[16];
#pragma unroll
  for (int i = 0; i < 16; ++i) acc[i] = 0.f;
  int pb = (2*py)*18 + 2*px;
  for (int ic = 0; ic < 64; ++ic) {
    const float* xr = sH + ic*324 + pb;
    const float* wr = wt3 + ic*1024 + ocq*16;
#pragma unroll
    for (int t = 0; t < 16; ++t) {
      float v = xr[(t>>2)*18 + (t&3)];
      const float* wv = wr + t*64;
#pragma unroll
      for (int i = 0; i < 16; ++i) acc[i] = fmaf(v, wv[i], acc[i]);
    }
  }
  int oy = r0 + py, ox = c0 + px;
  if (oy < 15 && ox < 15) {
    int p2 = oy*15 + ox;
#pragma unroll
    for (int i = 0; i < 16; ++i) {
      int oc = ocq*16 + i;
      y[(size_t)s*NSTATE + p2*64 + oc] = acc[i] + b3c[oc];
    }
  }
}

// ============================ head =========================================
__global__ __launch_bounds__(256)
void head_kernel(const float* __restrict__ y,
    const float* __restrict__ k1, const float* __restrict__ k3,
    const float* __restrict__ k4, const float* __restrict__ k5,
    const float* __restrict__ k6,
    float c1, float c3, float c4, float c5, float c6,
    const float* __restrict__ og, const float* __restrict__ ob,
    const float* __restrict__ fcw, const float* __restrict__ fcb,
    float* __restrict__ out)
{
  __shared__ float sY[NSTATE];          // [pix][ch]
  __shared__ float sA[64], sB[64], sM[64];
  int tid = threadIdx.x, s = blockIdx.x;
  size_t base = (size_t)s * NSTATE;
  for (int e = tid; e < NSTATE; e += 256) {
    float v = y[base + e];
    v = fmaf(c1, k1[base + e], v);
    v = fmaf(c3, k3[base + e], v);
    v = fmaf(c4, k4[base + e], v);
    v = fmaf(c5, k5[base + e], v);
    v = fmaf(c6, k6[base + e], v);
    sY[e] = v;
  }
  __syncthreads();
  {
    int g = tid >> 3, lane = tid & 7, c0 = 2*g;   // 32 groups x 8 lanes
    float ssum = 0.f, q = 0.f;
    for (int pix = lane; pix < NPIX; pix += 8) {
      float v0 = sY[pix*64 + c0], v1 = sY[pix*64 + c0 + 1];
      ssum += v0 + v1; q = fmaf(v0, v0, fmaf(v1, v1, q));
    }
#pragma unroll
    for (int m = 1; m < 8; m <<= 1) { ssum += __shfl_xor(ssum, m); q += __shfl_xor(q, m); }
    if (lane == 0) {
      float mu = ssum*(1.f/450.f);
      float var = fmaf(-mu, mu, q*(1.f/450.f));
      float rs = 1.f / sqrtf(var + 1e-5f);
      float a0 = rs*og[c0], a1 = rs*og[c0+1];
      sA[c0]   = a0; sB[c0]   = fmaf(-mu, a0, ob[c0]);
      sA[c0+1] = a1; sB[c0+1] = fmaf(-mu, a1, ob[c0+1]);
    }
    __syncthreads();
  }
  {
    int c = tid >> 2, l = tid & 3;
    float m = 0.f;
    for (int pix = l; pix < NPIX; pix += 4)
      m += fmaxf(0.f, fmaf(sA[c], sY[pix*64 + c], sB[c]));
#pragma unroll
    for (int mm = 1; mm < 4; mm <<= 1) m += __shfl_xor(m, mm);
    if (l == 0) sM[c] = m * (1.f/225.f);
  }
  __syncthreads();
  if (tid < 10) {
    float v = fcb[tid];
    const float* wr = fcw + tid*64;
    for (int c = 0; c < 64; ++c) v = fmaf(sM[c], wr[c], v);
    out[s*10 + tid] = v;
  }
}

// ============================ host =========================================
extern "C" void kernel_launch(void* const* d_in, const int* in_sizes, int n_in,
                              void* d_out, int out_size, void* d_ws, size_t ws_size,
                              hipStream_t stream)
{
  const float* x    = (const float*)d_in[0];
  const float* w1   = (const float*)d_in[1];
  const float* b1   = (const float*)d_in[2];
  const float* g1g  = (const float*)d_in[3];
  const float* g1b  = (const float*)d_in[4];
  const float* w2   = (const float*)d_in[5];
  const float* b2   = (const float*)d_in[6];
  const float* g2g  = (const float*)d_in[7];
  const float* g2b  = (const float*)d_in[8];
  const float* w3   = (const float*)d_in[9];
  const float* b3   = (const float*)d_in[10];
  const float* fg1g = (const float*)d_in[11];
  const float* fg1b = (const float*)d_in[12];
  const float* fw1  = (const float*)d_in[13];
  const float* fb1  = (const float*)d_in[14];
  const float* fg2g = (const float*)d_in[15];
  const float* fg2b = (const float*)d_in[16];
  const float* fw2  = (const float*)d_in[17];
  const float* fb2  = (const float*)d_in[18];
  const float* fg3g = (const float*)d_in[19];
  const float* fg3b = (const float*)d_in[20];
  const float* ogg  = (const float*)d_in[21];
  const float* ogb  = (const float*)d_in[22];
  const float* fcw  = (const float*)d_in[23];
  const float* fcb  = (const float*)d_in[24];
  float* out = (float*)d_out;

  char* ws = (char*)d_ws;
  size_t off = 0;
  auto alloc = [&](size_t bytes) -> void* {
    void* p = ws + off; off += (bytes + 255) & ~(size_t)255; return p;
  };
  const size_t NST = (size_t)NSAMP * NSTATE;
  float* y = (float*)alloc(NST * 4);
  char* kbase = ws + off;
  float* k[6];
  for (int i = 0; i < 6; ++i) k[i] = (float*)alloc(NST * 4);
  float* h2raw = (float*)kbase;                     // overlap: dead before k's used
  float* gn1A = (float*)alloc(256*64*4);
  float* gn1B = (float*)alloc(256*64*4);
  float* gn2A = (float*)alloc(256*64*4);
  float* gn2B = (float*)alloc(256*64*4);
  float* gsum = (float*)alloc(256*32*4);
  float* gsq  = (float*)alloc(256*32*4);
  float* wt2  = (float*)alloc(64*16*64*4);
  float* wt3  = (float*)alloc(64*16*64*4);
  unsigned short* wtb1 = (unsigned short*)alloc(9*64*64*2);
  unsigned short* wtb2 = (unsigned short*)alloc(9*64*64*2);
  float* ts1  = (float*)alloc(576*4);
  float* ts2  = (float*)alloc(576*4);
  if (off > ws_size) return;

  hipMemsetAsync(gsum, 0, 256*32*4, stream);
  hipMemsetAsync(gsq,  0, 256*32*4, stream);

  transpose_weights<<<256, 256, 0, stream>>>(w2, w3, fw1, fw2, wt2, wt3,
                                             wtb1, wtb2, ts1, ts2);
  gn1_stats_kernel<<<256*32, 256, 0, stream>>>(x, w1, b1, g1g, g1b, gn1A, gn1B);
  conv2_kernel<<<dim3(16, 256), 256, 0, stream>>>(x, w1, b1, gn1A, gn1B, wt2, b2,
                                                  h2raw, gsum, gsq);
  gn2_finalize<<<32, 256, 0, stream>>>(gsum, gsq, g2g, g2b, gn2A, gn2B);
  conv3_kernel<<<dim3(4, 256), 256, 0, stream>>>(h2raw, gn2A, gn2B, wt3, b3, y);

  const double hs = 1.0/8.0;
  const double A21 = 1.0/5, A31 = 3./40, A32 = 9./40,
      A41 = 44./45, A42 = -56./15, A43 = 32./9,
      A51 = 19372./6561, A52 = -25360./2187, A53 = 64448./6561, A54 = -212./729,
      A61 = 9017./3168, A62 = -355./33, A63 = 46732./5247, A64 = 49./176, A65 = -5103./18656,
      B1 = 35./384, B3 = 500./1113, B4 = 125./192, B5 = -2187./6784, B6 = 11./84;

  auto stage = [&](int writeY, int nc,
                   const float* kA, double cA, const float* kB, double cB,
                   const float* kC, double cC, const float* kD, double cD,
                   const float* kE, double cE, double t, float* kout) {
    ode_stage<<<256, 512, 0, stream>>>(y, y, writeY, nc,
        kA, (float)(hs*cA), kB, (float)(hs*cB), kC, (float)(hs*cC),
        kD, (float)(hs*cD), kE, (float)(hs*cE), (float)t,
        wtb1, fb1, ts1, wtb2, fb2, ts2,
        fg1g, fg1b, fg2g, fg2b, fg3g, fg3b, kout);
  };

  for (int i = 0; i < 8; ++i) {
    double t0 = i * hs;
    if (i == 0) stage(0, 0, y,0, y,0, y,0, y,0, y,0, t0, k[0]);
    else        stage(1, 5, k[0],B1, k[2],B3, k[3],B4, k[4],B5, k[5],B6, t0, k[0]);
    stage(0, 1, k[0],A21, y,0,      y,0,      y,0,      y,0,      t0 + hs*(1.0/5), k[1]);
    stage(0, 2, k[0],A31, k[1],A32, y,0,      y,0,      y,0,      t0 + hs*0.3,     k[2]);
    stage(0, 3, k[0],A41, k[1],A42, k[2],A43, y,0,      y,0,      t0 + hs*0.8,     k[3]);
    stage(0, 4, k[0],A51, k[1],A52, k[2],A53, k[3],A54, y,0,      t0 + hs*(8.0/9), k[4]);
    stage(0, 5, k[0],A61, k[1],A62, k[2],A63, k[3],A64, k[4],A65, t0 + hs,         k[5]);
  }
  head_kernel<<<256, 256, 0, stream>>>(y, k[0], k[2], k[3], k[4], k[5],
      (float)(hs*B1), (float)(hs*B3), (float)(hs*B4), (float)(hs*B5), (float)(hs*B6),
      ogg, ogb, fcw, fcb, out);
}

// Round 11
// 3097.648 us; speedup vs baseline: 4.2208x; 1.2220x over previous
//
#include <hip/hip_runtime.h>
#include <math.h>

// ---------------------------------------------------------------------------
// ODENet forward. ODE stage + conv2 use bf16 MFMA implicit-GEMM; state f32.
//   state: [256, 225 pix, 64 ch]  (channel-last, f32)
// ---------------------------------------------------------------------------

#define NSAMP 256
#define NCH   64
#define NPIX  225           // 15*15
#define NSTATE (NCH*NPIX)   // 14400 per sample
#define CSX   72            // ushort stride of sXc rows (bank-stride 4)
#define CSY   68            // f32 stride of sYc rows (bank-stride 4)
#define XROWS 306           // 18*17 padded rows (covers ghost pixels 225..239)
#define CSH   68            // ushort stride of conv2 sH rows (bank-stride 2)

typedef __attribute__((ext_vector_type(8))) short  sh8;
typedef __attribute__((ext_vector_type(4))) float  f32x4;
typedef __attribute__((ext_vector_type(2))) float  f32x2;

__device__ __forceinline__ unsigned short f2bf(float f) {
  unsigned u = __float_as_uint(f);
  u += 0x7FFFu + ((u >> 16) & 1u);        // RNE
  return (unsigned short)(u >> 16);
}

// ======================= fused ODE stage (MFMA) ============================
// block = one sample, 512 threads = 8 waves.
// wave w: och = w&1 (oc 32*och..+32, held as 2 oc-tiles of weights in regs),
//         pg = w>>1 (pixel-tile group: 4,4,4,3 tiles of 16 pixels).

__device__ __forceinline__ void gn_stats_cl(const float* sYc,
    const float* __restrict__ gamma, const float* __restrict__ beta,
    float* sA, float* sB, int tid)
{
  int g = tid >> 4, lane = tid & 15, c0 = g*2;   // 32 groups x 16 lanes
  float s = 0.f, q = 0.f;
  for (int pix = lane; pix < NPIX; pix += 16) {
    f32x2 v = *(const f32x2*)&sYc[pix*CSY + c0];
    s += v.x + v.y;
    q = fmaf(v.x, v.x, fmaf(v.y, v.y, q));
  }
#pragma unroll
  for (int m = 1; m < 16; m <<= 1) { s += __shfl_xor(s, m); q += __shfl_xor(q, m); }
  if (lane == 0) {
    float mu  = s * (1.f/450.f);
    float var = fmaf(-mu, mu, q * (1.f/450.f));
    float rs  = 1.f / sqrtf(var + 1e-5f);
    float a0 = rs*gamma[c0], a1 = rs*gamma[c0+1];
    sA[c0]   = a0; sB[c0]   = fmaf(-mu, a0, beta[c0]);
    sA[c0+1] = a1; sB[c0+1] = fmaf(-mu, a1, beta[c0+1]);
  }
  __syncthreads();
}

// relu(GN(x)) -> padded channel-last bf16
__device__ __forceinline__ void build_sxc(const float* sYc, unsigned short* sXc,
    const float* sA, const float* sB, int tid)
{
  for (int e = tid; e < XROWS*32; e += 512) {
    int prow = e >> 5, cp = e & 31, c0 = cp*2;
    int r = prow/17, cc = prow - r*17;
    unsigned pack = 0u;
    if (r >= 1 && r <= 15 && cc >= 1 && cc <= 15) {
      int pix = (r-1)*15 + (cc-1);
      f32x2 v = *(const f32x2*)&sYc[pix*CSY + c0];
      float a0 = fmaxf(0.f, fmaf(sA[c0],   v.x, sB[c0]));
      float a1 = fmaxf(0.f, fmaf(sA[c0+1], v.y, sB[c0+1]));
      pack = (unsigned)f2bf(a0) | ((unsigned)f2bf(a1) << 16);
    }
    *(unsigned*)&sXc[prow*CSX + c0] = pack;
  }
  __syncthreads();
}

// one 64->64 3x3 conv via mfma_f32_16x16x32_bf16; t-channel via class table.
__device__ __forceinline__ void conv_mfma(const unsigned short* sXc, float* sYc,
    const sh8* w0, const sh8* w1r,
    const float* __restrict__ bias, const float* __restrict__ ts, float tval,
    int och, int pg, int l)
{
  int lr = l & 15, lg = l >> 4;
  int nt = (pg < 3) ? 4 : 3;
  for (int ti = 0; ti < nt; ++ti) {
    int pt = pg*4 + ti;
    int pix = pt*16 + lr;                 // 0..239 (225..239 = ghost)
    int py = pix/15, px = pix - py*15;
    const unsigned short* bp = sXc + ((py*17 + px)*CSX + lg*8);
    f32x4 a0 = {0.f,0.f,0.f,0.f}, a1 = {0.f,0.f,0.f,0.f};
#pragma unroll
    for (int kb = 0; kb < 18; ++kb) {
      int tap = kb >> 1;
      int off = ((tap/3)*17 + (tap%3))*CSX + (kb & 1)*32;   // compile-time
      sh8 b = *(const sh8*)(bp + off);
      a0 = __builtin_amdgcn_mfma_f32_16x16x32_bf16(w0[kb],  b, a0, 0, 0, 0);
      a1 = __builtin_amdgcn_mfma_f32_16x16x32_bf16(w1r[kb], b, a1, 0, 0, 0);
    }
    if (pix < NPIX) {
      int cy = (py == 0) ? 0 : ((py == 14) ? 2 : 1);
      int cx = (px == 0) ? 0 : ((px == 14) ? 2 : 1);
      const float* tsp = ts + (cy*3 + cx)*64;
      int ocb = och*32 + lg*4;
      f32x4 o0, o1;
#pragma unroll
      for (int r = 0; r < 4; ++r) {
        o0[r] = a0[r] + bias[ocb+r]    + tval*tsp[ocb+r];
        o1[r] = a1[r] + bias[ocb+16+r] + tval*tsp[ocb+16+r];
      }
      *(f32x4*)&sYc[pix*CSY + ocb]      = o0;
      *(f32x4*)&sYc[pix*CSY + ocb + 16] = o1;
    }
  }
}

__global__ __launch_bounds__(512, 2)
void ode_stage(const float* y, float* ywr, int writeY, int nc,
    const float* __restrict__ kA, float cA,
    const float* __restrict__ kB, float cB,
    const float* __restrict__ kC, float cC,
    const float* __restrict__ kD, float cD,
    const float* __restrict__ kE, float cE,
    float tval,
    const unsigned short* __restrict__ wb1, const float* __restrict__ bias1,
    const float* __restrict__ ts1,
    const unsigned short* __restrict__ wb2, const float* __restrict__ bias2,
    const float* __restrict__ ts2,
    const float* __restrict__ g1, const float* __restrict__ b1,
    const float* __restrict__ g2, const float* __restrict__ b2,
    const float* __restrict__ g3, const float* __restrict__ b3,
    float* __restrict__ kout)
{
  __shared__ float         sYc[NPIX*CSY];     // 61.2 KB
  __shared__ unsigned short sXc[XROWS*CSX];   // 44.1 KB
  __shared__ float sA[64], sB[64];

  int tid = threadIdx.x, l = tid & 63, w = tid >> 6;
  int och = w & 1, pg = w >> 1;
  int lr = l & 15, lg = l >> 4;
  size_t base = (size_t)blockIdx.x * NSTATE;

  // preload conv1 weights into regs: 2 oc-tiles x 18 K-steps (144 VGPR)
  sh8 w0[18], w1r[18];
  {
    const unsigned short* p0 = wb1 + ((och*32 + lr)*64 + lg*8);
    const unsigned short* p1 = p0 + 16*64;
#pragma unroll
    for (int kb = 0; kb < 18; ++kb) {
      int off = (kb >> 1)*4096 + (kb & 1)*32;
      w0[kb]  = *(const sh8*)(p0 + off);
      w1r[kb] = *(const sh8*)(p1 + off);
    }
  }

  // RK combine (global [pix][ch] f32) -> sYc; optionally persist new y
  for (int e = tid; e < 3600; e += 512) {
    size_t g = base + (size_t)e*4;
    f32x4 v = *(const f32x4*)(y + g);
    if (nc > 0) { f32x4 t = *(const f32x4*)(kA + g); v += cA*t; }
    if (nc > 1) { f32x4 t = *(const f32x4*)(kB + g); v += cB*t; }
    if (nc > 2) { f32x4 t = *(const f32x4*)(kC + g); v += cC*t; }
    if (nc > 3) { f32x4 t = *(const f32x4*)(kD + g); v += cD*t; }
    if (nc > 4) { f32x4 t = *(const f32x4*)(kE + g); v += cE*t; }
    if (writeY) *(f32x4*)(ywr + g) = v;
    int pix = e >> 4, q = e & 15;
    *(f32x4*)&sYc[pix*CSY + q*4] = v;
  }
  __syncthreads();

  gn_stats_cl(sYc, g1, b1, sA, sB, tid);                 // f_gn1
  build_sxc(sYc, sXc, sA, sB, tid);                      // relu + pad -> bf16
  conv_mfma(sXc, sYc, w0, w1r, bias1, ts1, tval, och, pg, l);   // f_conv1

  { // preload conv2 weights (register-only; no LDS hazard)
    const unsigned short* p0 = wb2 + ((och*32 + lr)*64 + lg*8);
    const unsigned short* p1 = p0 + 16*64;
#pragma unroll
    for (int kb = 0; kb < 18; ++kb) {
      int off = (kb >> 1)*4096 + (kb & 1)*32;
      w0[kb]  = *(const sh8*)(p0 + off);
      w1r[kb] = *(const sh8*)(p1 + off);
    }
  }
  __syncthreads();

  gn_stats_cl(sYc, g2, b2, sA, sB, tid);                 // f_gn2
  build_sxc(sYc, sXc, sA, sB, tid);
  conv_mfma(sXc, sYc, w0, w1r, bias2, ts2, tval, och, pg, l);   // f_conv2
  __syncthreads();

  gn_stats_cl(sYc, g3, b3, sA, sB, tid);                 // f_gn3 (no relu)

  for (int e = tid; e < 3600; e += 512) {
    int pix = e >> 4, q = e & 15, c0 = q*4;
    f32x4 v = *(const f32x4*)&sYc[pix*CSY + c0];
    f32x4 o;
#pragma unroll
    for (int r = 0; r < 4; ++r) o[r] = fmaf(sA[c0+r], v[r], sB[c0+r]);
    *(f32x4*)(kout + base + (size_t)e*4) = o;
  }
}

// ============================ weight prep ==================================
// wt3: [ic][tap][oc] f32 (conv3). wtb2c: [tap][oc][ic] bf16 (conv2 MFMA).
// wtb1/wtb2: [tap][oc][ch] bf16 (ODE convs, real channels = ic 1..64).
// ts1/ts2: [class 3x3][oc] f32 = sum of t-channel taps valid per boundary class.
__global__ void transpose_weights(
    const float* __restrict__ w2, const float* __restrict__ w3,
    const float* __restrict__ wf1, const float* __restrict__ wf2,
    unsigned short* __restrict__ wtb2c, float* __restrict__ wt3,
    unsigned short* __restrict__ wtb1, unsigned short* __restrict__ wtb2,
    float* __restrict__ ts1, float* __restrict__ ts2)
{
  int i = blockIdx.x*256 + threadIdx.x;
  if (i < 64*16*64) {              // conv3: [ic 64][tap 16][oc 64] f32
    int ic = i >> 10, rem = i & 1023, tap = rem >> 6, oc = rem & 63;
    wt3[i] = w3[(oc*64 + ic)*16 + tap];
  }
  if (i < 16*64*64) {              // conv2 MFMA: [tap 16][oc 64][ic 64] bf16
    int tap = i >> 12, oc = (i >> 6) & 63, ic = i & 63;
    wtb2c[i] = f2bf(w2[(oc*64 + ic)*16 + tap]);
  }
  if (i < 9*64*64) {               // [tap][oc][ch]
    int tap = i >> 12, oc = (i >> 6) & 63, ch = i & 63;
    wtb1[i] = f2bf(wf1[(oc*65 + ch + 1)*9 + tap]);
    wtb2[i] = f2bf(wf2[(oc*65 + ch + 1)*9 + tap]);
  }
  if (i < 576) {                   // t-channel class sums
    int cls = i >> 6, oc = i & 63;
    int cy = cls/3, cx = cls - cy*3;
    int dy0 = (cy == 0) ? 1 : 0, dy1 = (cy == 2) ? 1 : 2;
    int dx0 = (cx == 0) ? 1 : 0, dx1 = (cx == 2) ? 1 : 2;
    float s1 = 0.f, s2 = 0.f;
    for (int dy = dy0; dy <= dy1; ++dy)
      for (int dx = dx0; dx <= dx1; ++dx) {
        s1 += wf1[(oc*65 + 0)*9 + dy*3 + dx];
        s2 += wf2[(oc*65 + 0)*9 + dy*3 + dx];
      }
    ts1[i] = s1; ts2[i] = s2;
  }
}

// ============================ phase A ======================================

__global__ __launch_bounds__(256)
void gn1_stats_kernel(const float* __restrict__ x,
    const float* __restrict__ w1, const float* __restrict__ b1,
    const float* __restrict__ g1g, const float* __restrict__ g1b,
    float* __restrict__ gn1A, float* __restrict__ gn1B)
{
  __shared__ float sXin[4096];
  __shared__ float red[16];
  int s = blockIdx.x >> 5, g = blockIdx.x & 31;
  int tid = threadIdx.x;
  const float* xs = x + (size_t)s*4096;
  for (int e = tid; e < 4096; e += 256) sXin[e] = xs[e];
  __syncthreads();
  int c0 = 2*g;
  float sum = 0.f, sq = 0.f;
  for (int e = tid; e < 2*3844; e += 256) {
    int hi = (e >= 3844);
    int c  = c0 + hi;
    int qq = e - hi*3844;
    int oy = qq / 62, ox = qq - oy*62;
    float v = b1[c];
#pragma unroll
    for (int ky = 0; ky < 3; ++ky)
#pragma unroll
    for (int kx = 0; kx < 3; ++kx)
      v = fmaf(sXin[(oy+ky)*64 + ox+kx], w1[c*9 + ky*3 + kx], v);
    sum += v; sq = fmaf(v, v, sq);
  }
#pragma unroll
  for (int m = 1; m < 64; m <<= 1) { sum += __shfl_xor(sum, m); sq += __shfl_xor(sq, m); }
  int w = tid >> 6;
  if ((tid & 63) == 0) { red[w] = sum; red[8+w] = sq; }
  __syncthreads();
  if (tid == 0) {
    float S = red[0]+red[1]+red[2]+red[3];
    float Q = red[8]+red[9]+red[10]+red[11];
    float n = 2.f*3844.f;
    float mu = S/n, var = fmaf(-mu, mu, Q/n);
    float rs = 1.f / sqrtf(var + 1e-5f);
    float a0 = rs*g1g[c0], a1 = rs*g1g[c0+1];
    gn1A[s*64+c0]   = a0; gn1B[s*64+c0]   = fmaf(-mu, a0, g1b[c0]);
    gn1A[s*64+c0+1] = a1; gn1B[s*64+c0+1] = fmaf(-mu, a1, g1b[c0+1]);
  }
}

// conv2 4x4 s2 p1 via MFMA implicit-GEMM. h1 recomputed on the fly (f32),
// staged channel-last bf16. Writes raw output + GN2 partial sums.
// block = 256 threads = 4 waves; wave wv = 16-oc tile; grid (16 tiles, 256 s).
__global__ __launch_bounds__(256)
void conv2_mfma(const float* __restrict__ x,
    const float* __restrict__ w1, const float* __restrict__ b1c,
    const float* __restrict__ gn1A, const float* __restrict__ gn1B,
    const unsigned short* __restrict__ wtb2c, const float* __restrict__ b2c,
    float* __restrict__ h2raw, float* __restrict__ gsum, float* __restrict__ gsq)
{
  __shared__ float sXin[400];            // 20x20 x-patch
  __shared__ unsigned short sH[324*CSH]; // 18x18 pixels x 64ch bf16 (44.1 KB)
  int tile = blockIdx.x, s = blockIdx.y;
  int r0 = (tile >> 2)*8, c0 = (tile & 3)*8;
  int tid = threadIdx.x;
  int by = 2*r0 - 1, bx = 2*c0 - 1;
  int l = tid & 63, wv = tid >> 6;       // wv = oc-tile 0..3
  int lr = l & 15, lg = l >> 4;

  const float* xs = x + (size_t)s*4096;
  for (int e = tid; e < 400; e += 256) {
    int r = e/20, c = e - r*20;
    int iy = by + r, ix = bx + c;
    sXin[e] = (iy >= 0 && iy < 64 && ix >= 0 && ix < 64) ? xs[iy*64 + ix] : 0.f;
  }

  // preload A-frags: 16 taps x 2 K-halves = 32 sh8 (128 VGPR), global only
  sh8 wa[32];
  {
    const unsigned short* p = wtb2c + ((wv*16 + lr)*64 + lg*8);
#pragma unroll
    for (int kb = 0; kb < 32; ++kb) {
      int off = (kb >> 1)*4096 + (kb & 1)*32;   // tap*64*64 + half*32
      wa[kb] = *(const sh8*)(p + off);
    }
  }
  __syncthreads();

  // h1 = relu(GN1(conv1(x))) -> channel-last bf16 patch
  const float* A  = gn1A + s*64;
  const float* Bb = gn1B + s*64;
  for (int e = tid; e < 324*32; e += 256) {
    int prow = e >> 5, cp = e & 31, cc0 = cp*2;
    int r = prow/18, c = prow - r*18;
    int iy = by + r, ix = bx + c;
    unsigned pack = 0u;
    if (iy >= 0 && iy < 62 && ix >= 0 && ix < 62) {
      float raw0 = b1c[cc0], raw1 = b1c[cc0+1];
#pragma unroll
      for (int ky = 0; ky < 3; ++ky)
#pragma unroll
      for (int kx = 0; kx < 3; ++kx) {
        float xv = sXin[(r+ky)*20 + c+kx];
        raw0 = fmaf(xv, w1[cc0*9 + ky*3 + kx], raw0);
        raw1 = fmaf(xv, w1[(cc0+1)*9 + ky*3 + kx], raw1);
      }
      float v0 = fmaxf(0.f, fmaf(A[cc0],   raw0, Bb[cc0]));
      float v1 = fmaxf(0.f, fmaf(A[cc0+1], raw1, Bb[cc0+1]));
      pack = (unsigned)f2bf(v0) | ((unsigned)f2bf(v1) << 16);
    }
    *(unsigned*)&sH[prow*CSH + cc0] = pack;
  }
  __syncthreads();

  // MFMA: 4 pixel-tiles of 16; D col = pixel (lr), row = oc (lg*4+reg)
  float pgl[4] = {0.f,0.f,0.f,0.f}, pql[4] = {0.f,0.f,0.f,0.f};
  for (int pt = 0; pt < 4; ++pt) {
    int p = pt*16 + lr;
    int py = p >> 3, px = p & 7;
    const unsigned short* bp = sH + ((2*py)*18 + 2*px)*CSH + lg*8;
    f32x4 acc = {0.f,0.f,0.f,0.f};
#pragma unroll
    for (int kb = 0; kb < 32; ++kb) {
      int tap = kb >> 1;
      int off = ((tap >> 2)*18 + (tap & 3))*CSH + (kb & 1)*32;  // compile-time
      sh8 b = *(const sh8*)(bp + off);
      acc = __builtin_amdgcn_mfma_f32_16x16x32_bf16(wa[kb], b, acc, 0, 0, 0);
    }
    int oy = r0 + py, ox = c0 + px;
    bool valid = (oy < 31) && (ox < 31);
#pragma unroll
    for (int r = 0; r < 4; ++r) {
      int oc = wv*16 + lg*4 + r;
      float v = valid ? acc[r] + b2c[oc] : 0.f;
      if (valid) h2raw[(((size_t)s*64 + oc)*31 + oy)*31 + ox] = v;
      pgl[r] += v; pql[r] = fmaf(v, v, pql[r]);
    }
  }
#pragma unroll
  for (int m = 1; m < 16; m <<= 1)
#pragma unroll
    for (int r = 0; r < 4; ++r) { pgl[r] += __shfl_xor(pgl[r], m); pql[r] += __shfl_xor(pql[r], m); }
  if (lr == 0) {
    int g0 = wv*8 + lg*2;                // group of oc pair
    atomicAdd(&gsum[s*32 + g0],     pgl[0] + pgl[1]);
    atomicAdd(&gsq [s*32 + g0],     pql[0] + pql[1]);
    atomicAdd(&gsum[s*32 + g0 + 1], pgl[2] + pgl[3]);
    atomicAdd(&gsq [s*32 + g0 + 1], pql[2] + pql[3]);
  }
}

__global__ void gn2_finalize(const float* __restrict__ gsum, const float* __restrict__ gsq,
    const float* __restrict__ g2g, const float* __restrict__ g2b,
    float* __restrict__ gn2A, float* __restrict__ gn2B)
{
  int i = blockIdx.x*256 + threadIdx.x;
  if (i >= 256*32) return;
  int s = i >> 5, g = i & 31;
  float n = 2.f*961.f;
  float mu = gsum[i]/n, var = fmaf(-mu, mu, gsq[i]/n);
  float rs = 1.f / sqrtf(var + 1e-5f);
  int c0 = 2*g;
  float a0 = rs*g2g[c0], a1 = rs*g2g[c0+1];
  gn2A[s*64+c0]   = a0; gn2B[s*64+c0]   = fmaf(-mu, a0, g2b[c0]);
  gn2A[s*64+c0+1] = a1; gn2B[s*64+c0+1] = fmaf(-mu, a1, g2b[c0+1]);
}

// conv3 4x4 s2 p1; writes y0 channel-last [s][pix][ch]
__global__ __launch_bounds__(256)
void conv3_kernel(const float* __restrict__ h2raw,
    const float* __restrict__ gn2A, const float* __restrict__ gn2B,
    const float* __restrict__ wt3, const float* __restrict__ b3c,
    float* __restrict__ y)
{
  __shared__ float sH[64*324];
  int tile = blockIdx.x, s = blockIdx.y;
  int r0 = (tile >> 1)*8, c0 = (tile & 1)*8;
  int tid = threadIdx.x;
  int by = 2*r0 - 1, bx = 2*c0 - 1;
  const float* A  = gn2A + s*64;
  const float* Bb = gn2B + s*64;
  for (int e = tid; e < 64*324; e += 256) {
    int ic = e/324, rem = e - ic*324;
    int r = rem/18, c = rem - r*18;
    int iy = by + r, ix = bx + c;
    float v = 0.f;
    if (iy >= 0 && iy < 31 && ix >= 0 && ix < 31) {
      float raw = h2raw[(((size_t)s*64 + ic)*31 + iy)*31 + ix];
      v = fmaxf(0.f, fmaf(A[ic], raw, Bb[ic]));
    }
    sH[e] = v;
  }
  __syncthreads();
  int ocq = __builtin_amdgcn_readfirstlane(tid >> 6);
  int p = tid & 63, py = p >> 3, px = p & 7;
  float acc[16];
#pragma unroll
  for (int i = 0; i < 16; ++i) acc[i] = 0.f;
  int pb = (2*py)*18 + 2*px;
  for (int ic = 0; ic < 64; ++ic) {
    const float* xr = sH + ic*324 + pb;
    const float* wr = wt3 + ic*1024 + ocq*16;
#pragma unroll
    for (int t = 0; t < 16; ++t) {
      float v = xr[(t>>2)*18 + (t&3)];
      const float* wv = wr + t*64;
#pragma unroll
      for (int i = 0; i < 16; ++i) acc[i] = fmaf(v, wv[i], acc[i]);
    }
  }
  int oy = r0 + py, ox = c0 + px;
  if (oy < 15 && ox < 15) {
    int p2 = oy*15 + ox;
#pragma unroll
    for (int i = 0; i < 16; ++i) {
      int oc = ocq*16 + i;
      y[(size_t)s*NSTATE + p2*64 + oc] = acc[i] + b3c[oc];
    }
  }
}

// ============================ head =========================================
__global__ __launch_bounds__(256)
void head_kernel(const float* __restrict__ y,
    const float* __restrict__ k1, const float* __restrict__ k3,
    const float* __restrict__ k4, const float* __restrict__ k5,
    const float* __restrict__ k6,
    float c1, float c3, float c4, float c5, float c6,
    const float* __restrict__ og, const float* __restrict__ ob,
    const float* __restrict__ fcw, const float* __restrict__ fcb,
    float* __restrict__ out)
{
  __shared__ float sY[NSTATE];          // [pix][ch]
  __shared__ float sA[64], sB[64], sM[64];
  int tid = threadIdx.x, s = blockIdx.x;
  size_t base = (size_t)s * NSTATE;
  for (int e = tid; e < NSTATE; e += 256) {
    float v = y[base + e];
    v = fmaf(c1, k1[base + e], v);
    v = fmaf(c3, k3[base + e], v);
    v = fmaf(c4, k4[base + e], v);
    v = fmaf(c5, k5[base + e], v);
    v = fmaf(c6, k6[base + e], v);
    sY[e] = v;
  }
  __syncthreads();
  {
    int g = tid >> 3, lane = tid & 7, c0 = 2*g;   // 32 groups x 8 lanes
    float ssum = 0.f, q = 0.f;
    for (int pix = lane; pix < NPIX; pix += 8) {
      float v0 = sY[pix*64 + c0], v1 = sY[pix*64 + c0 + 1];
      ssum += v0 + v1; q = fmaf(v0, v0, fmaf(v1, v1, q));
    }
#pragma unroll
    for (int m = 1; m < 8; m <<= 1) { ssum += __shfl_xor(ssum, m); q += __shfl_xor(q, m); }
    if (lane == 0) {
      float mu = ssum*(1.f/450.f);
      float var = fmaf(-mu, mu, q*(1.f/450.f));
      float rs = 1.f / sqrtf(var + 1e-5f);
      float a0 = rs*og[c0], a1 = rs*og[c0+1];
      sA[c0]   = a0; sB[c0]   = fmaf(-mu, a0, ob[c0]);
      sA[c0+1] = a1; sB[c0+1] = fmaf(-mu, a1, ob[c0+1]);
    }
    __syncthreads();
  }
  {
    int c = tid >> 2, l = tid & 3;
    float m = 0.f;
    for (int pix = l; pix < NPIX; pix += 4)
      m += fmaxf(0.f, fmaf(sA[c], sY[pix*64 + c], sB[c]));
#pragma unroll
    for (int mm = 1; mm < 4; mm <<= 1) m += __shfl_xor(m, mm);
    if (l == 0) sM[c] = m * (1.f/225.f);
  }
  __syncthreads();
  if (tid < 10) {
    float v = fcb[tid];
    const float* wr = fcw + tid*64;
    for (int c = 0; c < 64; ++c) v = fmaf(sM[c], wr[c], v);
    out[s*10 + tid] = v;
  }
}

// ============================ host =========================================
extern "C" void kernel_launch(void* const* d_in, const int* in_sizes, int n_in,
                              void* d_out, int out_size, void* d_ws, size_t ws_size,
                              hipStream_t stream)
{
  const float* x    = (const float*)d_in[0];
  const float* w1   = (const float*)d_in[1];
  const float* b1   = (const float*)d_in[2];
  const float* g1g  = (const float*)d_in[3];
  const float* g1b  = (const float*)d_in[4];
  const float* w2   = (const float*)d_in[5];
  const float* b2   = (const float*)d_in[6];
  const float* g2g  = (const float*)d_in[7];
  const float* g2b  = (const float*)d_in[8];
  const float* w3   = (const float*)d_in[9];
  const float* b3   = (const float*)d_in[10];
  const float* fg1g = (const float*)d_in[11];
  const float* fg1b = (const float*)d_in[12];
  const float* fw1  = (const float*)d_in[13];
  const float* fb1  = (const float*)d_in[14];
  const float* fg2g = (const float*)d_in[15];
  const float* fg2b = (const float*)d_in[16];
  const float* fw2  = (const float*)d_in[17];
  const float* fb2  = (const float*)d_in[18];
  const float* fg3g = (const float*)d_in[19];
  const float* fg3b = (const float*)d_in[20];
  const float* ogg  = (const float*)d_in[21];
  const float* ogb  = (const float*)d_in[22];
  const float* fcw  = (const float*)d_in[23];
  const float* fcb  = (const float*)d_in[24];
  float* out = (float*)d_out;

  char* ws = (char*)d_ws;
  size_t off = 0;
  auto alloc = [&](size_t bytes) -> void* {
    void* p = ws + off; off += (bytes + 255) & ~(size_t)255; return p;
  };
  const size_t NST = (size_t)NSAMP * NSTATE;
  float* y = (float*)alloc(NST * 4);
  char* kbase = ws + off;
  float* k[6];
  for (int i = 0; i < 6; ++i) k[i] = (float*)alloc(NST * 4);
  float* h2raw = (float*)kbase;                     // overlap: dead before k's used
  float* gn1A = (float*)alloc(256*64*4);
  float* gn1B = (float*)alloc(256*64*4);
  float* gn2A = (float*)alloc(256*64*4);
  float* gn2B = (float*)alloc(256*64*4);
  float* gsum = (float*)alloc(256*32*4);
  float* gsq  = (float*)alloc(256*32*4);
  unsigned short* wtb2c = (unsigned short*)alloc(16*64*64*2);
  float* wt3  = (float*)alloc(64*16*64*4);
  unsigned short* wtb1 = (unsigned short*)alloc(9*64*64*2);
  unsigned short* wtb2 = (unsigned short*)alloc(9*64*64*2);
  float* ts1  = (float*)alloc(576*4);
  float* ts2  = (float*)alloc(576*4);
  if (off > ws_size) return;

  hipMemsetAsync(gsum, 0, 256*32*4, stream);
  hipMemsetAsync(gsq,  0, 256*32*4, stream);

  transpose_weights<<<256, 256, 0, stream>>>(w2, w3, fw1, fw2, wtb2c, wt3,
                                             wtb1, wtb2, ts1, ts2);
  gn1_stats_kernel<<<256*32, 256, 0, stream>>>(x, w1, b1, g1g, g1b, gn1A, gn1B);
  conv2_mfma<<<dim3(16, 256), 256, 0, stream>>>(x, w1, b1, gn1A, gn1B, wtb2c, b2,
                                                h2raw, gsum, gsq);
  gn2_finalize<<<32, 256, 0, stream>>>(gsum, gsq, g2g, g2b, gn2A, gn2B);
  conv3_kernel<<<dim3(4, 256), 256, 0, stream>>>(h2raw, gn2A, gn2B, wt3, b3, y);

  const double hs = 1.0/8.0;
  const double A21 = 1.0/5, A31 = 3./40, A32 = 9./40,
      A41 = 44./45, A42 = -56./15, A43 = 32./9,
      A51 = 19372./6561, A52 = -25360./2187, A53 = 64448./6561, A54 = -212./729,
      A61 = 9017./3168, A62 = -355./33, A63 = 46732./5247, A64 = 49./176, A65 = -5103./18656,
      B1 = 35./384, B3 = 500./1113, B4 = 125./192, B5 = -2187./6784, B6 = 11./84;

  auto stage = [&](int writeY, int nc,
                   const float* kA, double cA, const float* kB, double cB,
                   const float* kC, double cC, const float* kD, double cD,
                   const float* kE, double cE, double t, float* kout) {
    ode_stage<<<256, 512, 0, stream>>>(y, y, writeY, nc,
        kA, (float)(hs*cA), kB, (float)(hs*cB), kC, (float)(hs*cC),
        kD, (float)(hs*cD), kE, (float)(hs*cE), (float)t,
        wtb1, fb1, ts1, wtb2, fb2, ts2,
        fg1g, fg1b, fg2g, fg2b, fg3g, fg3b, kout);
  };

  for (int i = 0; i < 8; ++i) {
    double t0 = i * hs;
    if (i == 0) stage(0, 0, y,0, y,0, y,0, y,0, y,0, t0, k[0]);
    else        stage(1, 5, k[0],B1, k[2],B3, k[3],B4, k[4],B5, k[5],B6, t0, k[0]);
    stage(0, 1, k[0],A21, y,0,      y,0,      y,0,      y,0,      t0 + hs*(1.0/5), k[1]);
    stage(0, 2, k[0],A31, k[1],A32, y,0,      y,0,      y,0,      t0 + hs*0.3,     k[2]);
    stage(0, 3, k[0],A41, k[1],A42, k[2],A43, y,0,      y,0,      t0 + hs*0.8,     k[3]);
    stage(0, 4, k[0],A51, k[1],A52, k[2],A53, k[3],A54, y,0,      t0 + hs*(8.0/9), k[4]);
    stage(0, 5, k[0],A61, k[1],A62, k[2],A63, k[3],A64, k[4],A65, t0 + hs,         k[5]);
  }
  head_kernel<<<256, 256, 0, stream>>>(y, k[0], k[2], k[3], k[4], k[5],
      (float)(hs*B1), (float)(hs*B3), (float)(hs*B4), (float)(hs*B5), (float)(hs*B6),
      ogg, ogb, fcw, fcb, out);
}

// Round 13
// 2772.900 us; speedup vs baseline: 4.7152x; 1.1171x over previous
//
#include <hip/hip_runtime.h>
#include <math.h>

// ---------------------------------------------------------------------------
// ODENet forward. ODE stage + conv2 + conv3 use bf16 MFMA implicit-GEMM.
//   state: [256, 225 pix, 64 ch]  (channel-last, f32)
// ---------------------------------------------------------------------------

#define NSAMP 256
#define NCH   64
#define NPIX  225           // 15*15
#define NSTATE (NCH*NPIX)   // 14400 per sample
#define CSX   72            // ushort stride of sXc rows (bank-stride 4)
#define CSY   68            // f32 stride of sYc rows (bank-stride 4)
#define XROWS 306           // 18*17 padded rows (covers ghost pixels 225..239)
#define CSH   68            // ushort stride of conv2/conv3 sH rows

typedef __attribute__((ext_vector_type(8))) short  sh8;
typedef __attribute__((ext_vector_type(4))) float  f32x4;
typedef __attribute__((ext_vector_type(2))) float  f32x2;

__device__ __forceinline__ unsigned short f2bf(float f) {
  unsigned u = __float_as_uint(f);
  u += 0x7FFFu + ((u >> 16) & 1u);        // RNE
  return (unsigned short)(u >> 16);
}

// ======================= fused ODE stage (MFMA) ============================
// block = one sample, 512 threads = 8 waves.
// wave w: och = w&1 (oc 32*och..+32, held as 2 oc-tiles of weights in regs),
//         pg = w>>1 (pixel-tile group: 4,4,4,3 tiles of 16 pixels).

__device__ __forceinline__ void gn_stats_cl(const float* sYc,
    const float* __restrict__ gamma, const float* __restrict__ beta,
    float* sA, float* sB, int tid)
{
  int g = tid >> 4, lane = tid & 15, c0 = g*2;   // 32 groups x 16 lanes
  float s = 0.f, q = 0.f;
  for (int pix = lane; pix < NPIX; pix += 16) {
    f32x2 v = *(const f32x2*)&sYc[pix*CSY + c0];
    s += v.x + v.y;
    q = fmaf(v.x, v.x, fmaf(v.y, v.y, q));
  }
#pragma unroll
  for (int m = 1; m < 16; m <<= 1) { s += __shfl_xor(s, m); q += __shfl_xor(q, m); }
  if (lane == 0) {
    float mu  = s * (1.f/450.f);
    float var = fmaf(-mu, mu, q * (1.f/450.f));
    float rs  = 1.f / sqrtf(var + 1e-5f);
    float a0 = rs*gamma[c0], a1 = rs*gamma[c0+1];
    sA[c0]   = a0; sB[c0]   = fmaf(-mu, a0, beta[c0]);
    sA[c0+1] = a1; sB[c0+1] = fmaf(-mu, a1, beta[c0+1]);
  }
  __syncthreads();
}

// relu(GN(x)) -> padded channel-last bf16
__device__ __forceinline__ void build_sxc(const float* sYc, unsigned short* sXc,
    const float* sA, const float* sB, int tid)
{
  for (int e = tid; e < XROWS*32; e += 512) {
    int prow = e >> 5, cp = e & 31, c0 = cp*2;
    int r = prow/17, cc = prow - r*17;
    unsigned pack = 0u;
    if (r >= 1 && r <= 15 && cc >= 1 && cc <= 15) {
      int pix = (r-1)*15 + (cc-1);
      f32x2 v = *(const f32x2*)&sYc[pix*CSY + c0];
      float a0 = fmaxf(0.f, fmaf(sA[c0],   v.x, sB[c0]));
      float a1 = fmaxf(0.f, fmaf(sA[c0+1], v.y, sB[c0+1]));
      pack = (unsigned)f2bf(a0) | ((unsigned)f2bf(a1) << 16);
    }
    *(unsigned*)&sXc[prow*CSX + c0] = pack;
  }
  __syncthreads();
}

// one 64->64 3x3 conv via mfma_f32_16x16x32_bf16; t-channel via class table.
__device__ __forceinline__ void conv_mfma(const unsigned short* sXc, float* sYc,
    const sh8* w0, const sh8* w1r,
    const float* __restrict__ bias, const float* __restrict__ ts, float tval,
    int och, int pg, int l)
{
  int lr = l & 15, lg = l >> 4;
  int nt = (pg < 3) ? 4 : 3;
  for (int ti = 0; ti < nt; ++ti) {
    int pt = pg*4 + ti;
    int pix = pt*16 + lr;                 // 0..239 (225..239 = ghost)
    int py = pix/15, px = pix - py*15;
    const unsigned short* bp = sXc + ((py*17 + px)*CSX + lg*8);
    f32x4 a0 = {0.f,0.f,0.f,0.f}, a1 = {0.f,0.f,0.f,0.f};
#pragma unroll
    for (int kb = 0; kb < 18; ++kb) {
      int tap = kb >> 1;
      int off = ((tap/3)*17 + (tap%3))*CSX + (kb & 1)*32;   // compile-time
      sh8 b = *(const sh8*)(bp + off);
      a0 = __builtin_amdgcn_mfma_f32_16x16x32_bf16(w0[kb],  b, a0, 0, 0, 0);
      a1 = __builtin_amdgcn_mfma_f32_16x16x32_bf16(w1r[kb], b, a1, 0, 0, 0);
    }
    if (pix < NPIX) {
      int cy = (py == 0) ? 0 : ((py == 14) ? 2 : 1);
      int cx = (px == 0) ? 0 : ((px == 14) ? 2 : 1);
      const float* tsp = ts + (cy*3 + cx)*64;
      int ocb = och*32 + lg*4;
      f32x4 o0, o1;
#pragma unroll
      for (int r = 0; r < 4; ++r) {
        o0[r] = a0[r] + bias[ocb+r]    + tval*tsp[ocb+r];
        o1[r] = a1[r] + bias[ocb+16+r] + tval*tsp[ocb+16+r];
      }
      *(f32x4*)&sYc[pix*CSY + ocb]      = o0;
      *(f32x4*)&sYc[pix*CSY + ocb + 16] = o1;
    }
  }
}

__global__ __launch_bounds__(512, 2)
void ode_stage(const float* y, float* ywr, int writeY, int nc,
    const float* __restrict__ kA, float cA,
    const float* __restrict__ kB, float cB,
    const float* __restrict__ kC, float cC,
    const float* __restrict__ kD, float cD,
    const float* __restrict__ kE, float cE,
    float tval,
    const unsigned short* __restrict__ wb1, const float* __restrict__ bias1,
    const float* __restrict__ ts1,
    const unsigned short* __restrict__ wb2, const float* __restrict__ bias2,
    const float* __restrict__ ts2,
    const float* __restrict__ g1, const float* __restrict__ b1,
    const float* __restrict__ g2, const float* __restrict__ b2,
    const float* __restrict__ g3, const float* __restrict__ b3,
    float* __restrict__ kout)
{
  __shared__ float         sYc[NPIX*CSY];     // 61.2 KB
  __shared__ unsigned short sXc[XROWS*CSX];   // 44.1 KB
  __shared__ float sA[64], sB[64];

  int tid = threadIdx.x, l = tid & 63, w = tid >> 6;
  int och = w & 1, pg = w >> 1;
  int lr = l & 15, lg = l >> 4;
  size_t base = (size_t)blockIdx.x * NSTATE;

  // preload conv1 weights into regs: 2 oc-tiles x 18 K-steps (144 VGPR)
  sh8 w0[18], w1r[18];
  {
    const unsigned short* p0 = wb1 + ((och*32 + lr)*64 + lg*8);
    const unsigned short* p1 = p0 + 16*64;
#pragma unroll
    for (int kb = 0; kb < 18; ++kb) {
      int off = (kb >> 1)*4096 + (kb & 1)*32;
      w0[kb]  = *(const sh8*)(p0 + off);
      w1r[kb] = *(const sh8*)(p1 + off);
    }
  }

  // RK combine (global [pix][ch] f32) -> sYc; optionally persist new y
  for (int e = tid; e < 3600; e += 512) {
    size_t g = base + (size_t)e*4;
    f32x4 v = *(const f32x4*)(y + g);
    if (nc > 0) { f32x4 t = *(const f32x4*)(kA + g); v += cA*t; }
    if (nc > 1) { f32x4 t = *(const f32x4*)(kB + g); v += cB*t; }
    if (nc > 2) { f32x4 t = *(const f32x4*)(kC + g); v += cC*t; }
    if (nc > 3) { f32x4 t = *(const f32x4*)(kD + g); v += cD*t; }
    if (nc > 4) { f32x4 t = *(const f32x4*)(kE + g); v += cE*t; }
    if (writeY) *(f32x4*)(ywr + g) = v;
    int pix = e >> 4, q = e & 15;
    *(f32x4*)&sYc[pix*CSY + q*4] = v;
  }
  __syncthreads();

  gn_stats_cl(sYc, g1, b1, sA, sB, tid);                 // f_gn1
  build_sxc(sYc, sXc, sA, sB, tid);                      // relu + pad -> bf16
  conv_mfma(sXc, sYc, w0, w1r, bias1, ts1, tval, och, pg, l);   // f_conv1

  { // preload conv2 weights (register-only; no LDS hazard)
    const unsigned short* p0 = wb2 + ((och*32 + lr)*64 + lg*8);
    const unsigned short* p1 = p0 + 16*64;
#pragma unroll
    for (int kb = 0; kb < 18; ++kb) {
      int off = (kb >> 1)*4096 + (kb & 1)*32;
      w0[kb]  = *(const sh8*)(p0 + off);
      w1r[kb] = *(const sh8*)(p1 + off);
    }
  }
  __syncthreads();

  gn_stats_cl(sYc, g2, b2, sA, sB, tid);                 // f_gn2
  build_sxc(sYc, sXc, sA, sB, tid);
  conv_mfma(sXc, sYc, w0, w1r, bias2, ts2, tval, och, pg, l);   // f_conv2
  __syncthreads();

  gn_stats_cl(sYc, g3, b3, sA, sB, tid);                 // f_gn3 (no relu)

  for (int e = tid; e < 3600; e += 512) {
    int pix = e >> 4, q = e & 15, c0 = q*4;
    f32x4 v = *(const f32x4*)&sYc[pix*CSY + c0];
    f32x4 o;
#pragma unroll
    for (int r = 0; r < 4; ++r) o[r] = fmaf(sA[c0+r], v[r], sB[c0+r]);
    *(f32x4*)(kout + base + (size_t)e*4) = o;
  }
}

// ============================ weight prep ==================================
// wtb2c/wtb3c: [tap][oc][ic] bf16 (conv2/conv3 MFMA).
// wtb1/wtb2: [tap][oc][ch] bf16 (ODE convs, real channels = ic 1..64).
// ts1/ts2: [class 3x3][oc] f32 = sum of t-channel taps valid per boundary class.
__global__ void transpose_weights(
    const float* __restrict__ w2, const float* __restrict__ w3,
    const float* __restrict__ wf1, const float* __restrict__ wf2,
    unsigned short* __restrict__ wtb2c, unsigned short* __restrict__ wtb3c,
    unsigned short* __restrict__ wtb1, unsigned short* __restrict__ wtb2,
    float* __restrict__ ts1, float* __restrict__ ts2)
{
  int i = blockIdx.x*256 + threadIdx.x;
  if (i < 16*64*64) {              // [tap 16][oc 64][ic 64] bf16
    int tap = i >> 12, oc = (i >> 6) & 63, ic = i & 63;
    wtb2c[i] = f2bf(w2[(oc*64 + ic)*16 + tap]);
    wtb3c[i] = f2bf(w3[(oc*64 + ic)*16 + tap]);
  }
  if (i < 9*64*64) {               // [tap][oc][ch]
    int tap = i >> 12, oc = (i >> 6) & 63, ch = i & 63;
    wtb1[i] = f2bf(wf1[(oc*65 + ch + 1)*9 + tap]);
    wtb2[i] = f2bf(wf2[(oc*65 + ch + 1)*9 + tap]);
  }
  if (i < 576) {                   // t-channel class sums
    int cls = i >> 6, oc = i & 63;
    int cy = cls/3, cx = cls - cy*3;
    int dy0 = (cy == 0) ? 1 : 0, dy1 = (cy == 2) ? 1 : 2;
    int dx0 = (cx == 0) ? 1 : 0, dx1 = (cx == 2) ? 1 : 2;
    float s1 = 0.f, s2 = 0.f;
    for (int dy = dy0; dy <= dy1; ++dy)
      for (int dx = dx0; dx <= dx1; ++dx) {
        s1 += wf1[(oc*65 + 0)*9 + dy*3 + dx];
        s2 += wf2[(oc*65 + 0)*9 + dy*3 + dx];
      }
    ts1[i] = s1; ts2[i] = s2;
  }
}

// ============================ phase A ======================================

__global__ __launch_bounds__(256)
void gn1_stats_kernel(const float* __restrict__ x,
    const float* __restrict__ w1, const float* __restrict__ b1,
    const float* __restrict__ g1g, const float* __restrict__ g1b,
    float* __restrict__ gn1A, float* __restrict__ gn1B)
{
  __shared__ float sXin[4096];
  __shared__ float red[16];
  int s = blockIdx.x >> 5, g = blockIdx.x & 31;
  int tid = threadIdx.x;
  const float* xs = x + (size_t)s*4096;
  for (int e = tid; e < 4096; e += 256) sXin[e] = xs[e];
  __syncthreads();
  int c0 = 2*g;
  float sum = 0.f, sq = 0.f;
  for (int e = tid; e < 2*3844; e += 256) {
    int hi = (e >= 3844);
    int c  = c0 + hi;
    int qq = e - hi*3844;
    int oy = qq / 62, ox = qq - oy*62;
    float v = b1[c];
#pragma unroll
    for (int ky = 0; ky < 3; ++ky)
#pragma unroll
    for (int kx = 0; kx < 3; ++kx)
      v = fmaf(sXin[(oy+ky)*64 + ox+kx], w1[c*9 + ky*3 + kx], v);
    sum += v; sq = fmaf(v, v, sq);
  }
#pragma unroll
  for (int m = 1; m < 64; m <<= 1) { sum += __shfl_xor(sum, m); sq += __shfl_xor(sq, m); }
  int w = tid >> 6;
  if ((tid & 63) == 0) { red[w] = sum; red[8+w] = sq; }
  __syncthreads();
  if (tid == 0) {
    float S = red[0]+red[1]+red[2]+red[3];
    float Q = red[8]+red[9]+red[10]+red[11];
    float n = 2.f*3844.f;
    float mu = S/n, var = fmaf(-mu, mu, Q/n);
    float rs = 1.f / sqrtf(var + 1e-5f);
    float a0 = rs*g1g[c0], a1 = rs*g1g[c0+1];
    gn1A[s*64+c0]   = a0; gn1B[s*64+c0]   = fmaf(-mu, a0, g1b[c0]);
    gn1A[s*64+c0+1] = a1; gn1B[s*64+c0+1] = fmaf(-mu, a1, g1b[c0+1]);
  }
}

// conv2 4x4 s2 p1 via MFMA implicit-GEMM. h1 recomputed on the fly (f32),
// staged channel-last bf16. Writes raw output + GN2 partial sums.
// block = 256 threads = 4 waves; wave wv = 16-oc tile; grid (16 tiles, 256 s).
__global__ __launch_bounds__(256)
void conv2_mfma(const float* __restrict__ x,
    const float* __restrict__ w1, const float* __restrict__ b1c,
    const float* __restrict__ gn1A, const float* __restrict__ gn1B,
    const unsigned short* __restrict__ wtb2c, const float* __restrict__ b2c,
    float* __restrict__ h2raw, float* __restrict__ gsum, float* __restrict__ gsq)
{
  __shared__ float sXin[400];            // 20x20 x-patch
  __shared__ unsigned short sH[324*CSH]; // 18x18 pixels x 64ch bf16 (44.1 KB)
  int tile = blockIdx.x, s = blockIdx.y;
  int r0 = (tile >> 2)*8, c0 = (tile & 3)*8;
  int tid = threadIdx.x;
  int by = 2*r0 - 1, bx = 2*c0 - 1;
  int l = tid & 63, wv = tid >> 6;       // wv = oc-tile 0..3
  int lr = l & 15, lg = l >> 4;

  const float* xs = x + (size_t)s*4096;
  for (int e = tid; e < 400; e += 256) {
    int r = e/20, c = e - r*20;
    int iy = by + r, ix = bx + c;
    sXin[e] = (iy >= 0 && iy < 64 && ix >= 0 && ix < 64) ? xs[iy*64 + ix] : 0.f;
  }

  // preload A-frags: 16 taps x 2 K-halves = 32 sh8 (128 VGPR), global only
  sh8 wa[32];
  {
    const unsigned short* p = wtb2c + ((wv*16 + lr)*64 + lg*8);
#pragma unroll
    for (int kb = 0; kb < 32; ++kb) {
      int off = (kb >> 1)*4096 + (kb & 1)*32;   // tap*64*64 + half*32
      wa[kb] = *(const sh8*)(p + off);
    }
  }
  __syncthreads();

  // h1 = relu(GN1(conv1(x))) -> channel-last bf16 patch
  const float* A  = gn1A + s*64;
  const float* Bb = gn1B + s*64;
  for (int e = tid; e < 324*32; e += 256) {
    int prow = e >> 5, cp = e & 31, cc0 = cp*2;
    int r = prow/18, c = prow - r*18;
    int iy = by + r, ix = bx + c;
    unsigned pack = 0u;
    if (iy >= 0 && iy < 62 && ix >= 0 && ix < 62) {
      float raw0 = b1c[cc0], raw1 = b1c[cc0+1];
#pragma unroll
      for (int ky = 0; ky < 3; ++ky)
#pragma unroll
      for (int kx = 0; kx < 3; ++kx) {
        float xv = sXin[(r+ky)*20 + c+kx];
        raw0 = fmaf(xv, w1[cc0*9 + ky*3 + kx], raw0);
        raw1 = fmaf(xv, w1[(cc0+1)*9 + ky*3 + kx], raw1);
      }
      float v0 = fmaxf(0.f, fmaf(A[cc0],   raw0, Bb[cc0]));
      float v1 = fmaxf(0.f, fmaf(A[cc0+1], raw1, Bb[cc0+1]));
      pack = (unsigned)f2bf(v0) | ((unsigned)f2bf(v1) << 16);
    }
    *(unsigned*)&sH[prow*CSH + cc0] = pack;
  }
  __syncthreads();

  // MFMA: 4 pixel-tiles of 16; D col = pixel (lr), row = oc (lg*4+reg)
  float pgl[4] = {0.f,0.f,0.f,0.f}, pql[4] = {0.f,0.f,0.f,0.f};
  for (int pt = 0; pt < 4; ++pt) {
    int p = pt*16 + lr;
    int py = p >> 3, px = p & 7;
    const unsigned short* bp = sH + ((2*py)*18 + 2*px)*CSH + lg*8;
    f32x4 acc = {0.f,0.f,0.f,0.f};
#pragma unroll
    for (int kb = 0; kb < 32; ++kb) {
      int tap = kb >> 1;
      int off = ((tap >> 2)*18 + (tap & 3))*CSH + (kb & 1)*32;  // compile-time
      sh8 b = *(const sh8*)(bp + off);
      acc = __builtin_amdgcn_mfma_f32_16x16x32_bf16(wa[kb], b, acc, 0, 0, 0);
    }
    int oy = r0 + py, ox = c0 + px;
    bool valid = (oy < 31) && (ox < 31);
#pragma unroll
    for (int r = 0; r < 4; ++r) {
      int oc = wv*16 + lg*4 + r;
      float v = valid ? acc[r] + b2c[oc] : 0.f;
      if (valid) h2raw[(((size_t)s*64 + oc)*31 + oy)*31 + ox] = v;
      pgl[r] += v; pql[r] = fmaf(v, v, pql[r]);
    }
  }
#pragma unroll
  for (int m = 1; m < 16; m <<= 1)
#pragma unroll
    for (int r = 0; r < 4; ++r) { pgl[r] += __shfl_xor(pgl[r], m); pql[r] += __shfl_xor(pql[r], m); }
  if (lr == 0) {
    int g0 = wv*8 + lg*2;                // group of oc pair
    atomicAdd(&gsum[s*32 + g0],     pgl[0] + pgl[1]);
    atomicAdd(&gsq [s*32 + g0],     pql[0] + pql[1]);
    atomicAdd(&gsum[s*32 + g0 + 1], pgl[2] + pgl[3]);
    atomicAdd(&gsq [s*32 + g0 + 1], pql[2] + pql[3]);
  }
}

__global__ void gn2_finalize(const float* __restrict__ gsum, const float* __restrict__ gsq,
    const float* __restrict__ g2g, const float* __restrict__ g2b,
    float* __restrict__ gn2A, float* __restrict__ gn2B)
{
  int i = blockIdx.x*256 + threadIdx.x;
  if (i >= 256*32) return;
  int s = i >> 5, g = i & 31;
  float n = 2.f*961.f;
  float mu = gsum[i]/n, var = fmaf(-mu, mu, gsq[i]/n);
  float rs = 1.f / sqrtf(var + 1e-5f);
  int c0 = 2*g;
  float a0 = rs*g2g[c0], a1 = rs*g2g[c0+1];
  gn2A[s*64+c0]   = a0; gn2B[s*64+c0]   = fmaf(-mu, a0, g2b[c0]);
  gn2A[s*64+c0+1] = a1; gn2B[s*64+c0+1] = fmaf(-mu, a1, g2b[c0+1]);
}

// conv3 4x4 s2 p1 via MFMA implicit-GEMM (clone of conv2_mfma).
// GN2+relu applied while staging h2raw channel-last bf16.
// Writes y0 channel-last [s][pix][ch]. grid (4 tiles, 256 s), 256 thr.
__global__ __launch_bounds__(256)
void conv3_mfma(const float* __restrict__ h2raw,
    const float* __restrict__ gn2A, const float* __restrict__ gn2B,
    const unsigned short* __restrict__ wtb3c, const float* __restrict__ b3c,
    float* __restrict__ y)
{
  __shared__ unsigned short sH[324*CSH]; // 44.1 KB
  int tile = blockIdx.x, s = blockIdx.y;
  int r0 = (tile >> 1)*8, c0 = (tile & 1)*8;
  int tid = threadIdx.x;
  int by = 2*r0 - 1, bx = 2*c0 - 1;
  int l = tid & 63, wv = tid >> 6;
  int lr = l & 15, lg = l >> 4;

  // preload A-frags
  sh8 wa[32];
  {
    const unsigned short* p = wtb3c + ((wv*16 + lr)*64 + lg*8);
#pragma unroll
    for (int kb = 0; kb < 32; ++kb) {
      int off = (kb >> 1)*4096 + (kb & 1)*32;
      wa[kb] = *(const sh8*)(p + off);
    }
  }

  // stage relu(GN2(h2raw)) -> channel-last bf16 (ic-major: coalesced reads)
  const float* A  = gn2A + s*64;
  const float* Bb = gn2B + s*64;
  for (int e = tid; e < 64*324; e += 256) {
    int ic = e/324, rem = e - ic*324;
    int r = rem/18, c = rem - r*18;
    int iy = by + r, ix = bx + c;
    unsigned short v = 0;
    if (iy >= 0 && iy < 31 && ix >= 0 && ix < 31) {
      float raw = h2raw[(((size_t)s*64 + ic)*31 + iy)*31 + ix];
      v = f2bf(fmaxf(0.f, fmaf(A[ic], raw, Bb[ic])));
    }
    sH[rem*CSH + ic] = v;
  }
  __syncthreads();

  // MFMA: 4 pixel-tiles of 16; D col = pixel (lr), row = oc (lg*4+reg)
  for (int pt = 0; pt < 4; ++pt) {
    int p = pt*16 + lr;
    int py = p >> 3, px = p & 7;
    const unsigned short* bp = sH + ((2*py)*18 + 2*px)*CSH + lg*8;
    f32x4 acc = {0.f,0.f,0.f,0.f};
#pragma unroll
    for (int kb = 0; kb < 32; ++kb) {
      int tap = kb >> 1;
      int off = ((tap >> 2)*18 + (tap & 3))*CSH + (kb & 1)*32;  // compile-time
      sh8 b = *(const sh8*)(bp + off);
      acc = __builtin_amdgcn_mfma_f32_16x16x32_bf16(wa[kb], b, acc, 0, 0, 0);
    }
    int oy = r0 + py, ox = c0 + px;
    if (oy < 15 && ox < 15) {
      int p2 = oy*15 + ox;
      int oc0 = wv*16 + lg*4;
      f32x4 o;
#pragma unroll
      for (int r = 0; r < 4; ++r) o[r] = acc[r] + b3c[oc0 + r];
      *(f32x4*)&y[(size_t)s*NSTATE + p2*64 + oc0] = o;
    }
  }
}

// ============================ head =========================================
__global__ __launch_bounds__(256)
void head_kernel(const float* __restrict__ y,
    const float* __restrict__ k1, const float* __restrict__ k3,
    const float* __restrict__ k4, const float* __restrict__ k5,
    const float* __restrict__ k6,
    float c1, float c3, float c4, float c5, float c6,
    const float* __restrict__ og, const float* __restrict__ ob,
    const float* __restrict__ fcw, const float* __restrict__ fcb,
    float* __restrict__ out)
{
  __shared__ float sY[NSTATE];          // [pix][ch]
  __shared__ float sA[64], sB[64], sM[64];
  int tid = threadIdx.x, s = blockIdx.x;
  size_t base = (size_t)s * NSTATE;
  for (int e = tid; e < NSTATE; e += 256) {
    float v = y[base + e];
    v = fmaf(c1, k1[base + e], v);
    v = fmaf(c3, k3[base + e], v);
    v = fmaf(c4, k4[base + e], v);
    v = fmaf(c5, k5[base + e], v);
    v = fmaf(c6, k6[base + e], v);
    sY[e] = v;
  }
  __syncthreads();
  {
    int g = tid >> 3, lane = tid & 7, c0 = 2*g;   // 32 groups x 8 lanes
    float ssum = 0.f, q = 0.f;
    for (int pix = lane; pix < NPIX; pix += 8) {
      float v0 = sY[pix*64 + c0], v1 = sY[pix*64 + c0 + 1];
      ssum += v0 + v1; q = fmaf(v0, v0, fmaf(v1, v1, q));
    }
#pragma unroll
    for (int m = 1; m < 8; m <<= 1) { ssum += __shfl_xor(ssum, m); q += __shfl_xor(q, m); }
    if (lane == 0) {
      float mu = ssum*(1.f/450.f);
      float var = fmaf(-mu, mu, q*(1.f/450.f));
      float rs = 1.f / sqrtf(var + 1e-5f);
      float a0 = rs*og[c0], a1 = rs*og[c0+1];
      sA[c0]   = a0; sB[c0]   = fmaf(-mu, a0, ob[c0]);
      sA[c0+1] = a1; sB[c0+1] = fmaf(-mu, a1, ob[c0+1]);
    }
    __syncthreads();
  }
  {
    int c = tid >> 2, l = tid & 3;
    float m = 0.f;
    for (int pix = l; pix < NPIX; pix += 4)
      m += fmaxf(0.f, fmaf(sA[c], sY[pix*64 + c], sB[c]));
#pragma unroll
    for (int mm = 1; mm < 4; mm <<= 1) m += __shfl_xor(m, mm);
    if (l == 0) sM[c] = m * (1.f/225.f);
  }
  __syncthreads();
  if (tid < 10) {
    float v = fcb[tid];
    const float* wr = fcw + tid*64;
    for (int c = 0; c < 64; ++c) v = fmaf(sM[c], wr[c], v);
    out[s*10 + tid] = v;
  }
}

// ============================ host =========================================
extern "C" void kernel_launch(void* const* d_in, const int* in_sizes, int n_in,
                              void* d_out, int out_size, void* d_ws, size_t ws_size,
                              hipStream_t stream)
{
  const float* x    = (const float*)d_in[0];
  const float* w1   = (const float*)d_in[1];
  const float* b1   = (const float*)d_in[2];
  const float* g1g  = (const float*)d_in[3];
  const float* g1b  = (const float*)d_in[4];
  const float* w2   = (const float*)d_in[5];
  const float* b2   = (const float*)d_in[6];
  const float* g2g  = (const float*)d_in[7];
  const float* g2b  = (const float*)d_in[8];
  const float* w3   = (const float*)d_in[9];
  const float* b3   = (const float*)d_in[10];
  const float* fg1g = (const float*)d_in[11];
  const float* fg1b = (const float*)d_in[12];
  const float* fw1  = (const float*)d_in[13];
  const float* fb1  = (const float*)d_in[14];
  const float* fg2g = (const float*)d_in[15];
  const float* fg2b = (const float*)d_in[16];
  const float* fw2  = (const float*)d_in[17];
  const float* fb2  = (const float*)d_in[18];
  const float* fg3g = (const float*)d_in[19];
  const float* fg3b = (const float*)d_in[20];
  const float* ogg  = (const float*)d_in[21];
  const float* ogb  = (const float*)d_in[22];
  const float* fcw  = (const float*)d_in[23];
  const float* fcb  = (const float*)d_in[24];
  float* out = (float*)d_out;

  char* ws = (char*)d_ws;
  size_t off = 0;
  auto alloc = [&](size_t bytes) -> void* {
    void* p = ws + off; off += (bytes + 255) & ~(size_t)255; return p;
  };
  const size_t NST = (size_t)NSAMP * NSTATE;
  float* y = (float*)alloc(NST * 4);
  char* kbase = ws + off;
  float* k[6];
  for (int i = 0; i < 6; ++i) k[i] = (float*)alloc(NST * 4);
  float* h2raw = (float*)kbase;                     // overlap: dead before k's used
  float* gn1A = (float*)alloc(256*64*4);
  float* gn1B = (float*)alloc(256*64*4);
  float* gn2A = (float*)alloc(256*64*4);
  float* gn2B = (float*)alloc(256*64*4);
  float* gsum = (float*)alloc(256*32*4);
  float* gsq  = (float*)alloc(256*32*4);
  unsigned short* wtb2c = (unsigned short*)alloc(16*64*64*2);
  unsigned short* wtb3c = (unsigned short*)alloc(16*64*64*2);
  unsigned short* wtb1 = (unsigned short*)alloc(9*64*64*2);
  unsigned short* wtb2 = (unsigned short*)alloc(9*64*64*2);
  float* ts1  = (float*)alloc(576*4);
  float* ts2  = (float*)alloc(576*4);
  if (off > ws_size) return;

  hipMemsetAsync(gsum, 0, 256*32*4, stream);
  hipMemsetAsync(gsq,  0, 256*32*4, stream);

  transpose_weights<<<256, 256, 0, stream>>>(w2, w3, fw1, fw2, wtb2c, wtb3c,
                                             wtb1, wtb2, ts1, ts2);
  gn1_stats_kernel<<<256*32, 256, 0, stream>>>(x, w1, b1, g1g, g1b, gn1A, gn1B);
  conv2_mfma<<<dim3(16, 256), 256, 0, stream>>>(x, w1, b1, gn1A, gn1B, wtb2c, b2,
                                                h2raw, gsum, gsq);
  gn2_finalize<<<32, 256, 0, stream>>>(gsum, gsq, g2g, g2b, gn2A, gn2B);
  conv3_mfma<<<dim3(4, 256), 256, 0, stream>>>(h2raw, gn2A, gn2B, wtb3c, b3, y);

  const double hs = 1.0/8.0;
  const double A21 = 1.0/5, A31 = 3./40, A32 = 9./40,
      A41 = 44./45, A42 = -56./15, A43 = 32./9,
      A51 = 19372./6561, A52 = -25360./2187, A53 = 64448./6561, A54 = -212./729,
      A61 = 9017./3168, A62 = -355./33, A63 = 46732./5247, A64 = 49./176, A65 = -5103./18656,
      B1 = 35./384, B3 = 500./1113, B4 = 125./192, B5 = -2187./6784, B6 = 11./84;

  auto stage = [&](int writeY, int nc,
                   const float* kA, double cA, const float* kB, double cB,
                   const float* kC, double cC, const float* kD, double cD,
                   const float* kE, double cE, double t, float* kout) {
    ode_stage<<<256, 512, 0, stream>>>(y, y, writeY, nc,
        kA, (float)(hs*cA), kB, (float)(hs*cB), kC, (float)(hs*cC),
        kD, (float)(hs*cD), kE, (float)(hs*cE), (float)t,
        wtb1, fb1, ts1, wtb2, fb2, ts2,
        fg1g, fg1b, fg2g, fg2b, fg3g, fg3b, kout);
  };

  for (int i = 0; i < 8; ++i) {
    double t0 = i * hs;
    if (i == 0) stage(0, 0, y,0, y,0, y,0, y,0, y,0, t0, k[0]);
    else        stage(1, 5, k[0],B1, k[2],B3, k[3],B4, k[4],B5, k[5],B6, t0, k[0]);
    stage(0, 1, k[0],A21, y,0,      y,0,      y,0,      y,0,      t0 + hs*(1.0/5), k[1]);
    stage(0, 2, k[0],A31, k[1],A32, y,0,      y,0,      y,0,      t0 + hs*0.3,     k[2]);
    stage(0, 3, k[0],A41, k[1],A42, k[2],A43, y,0,      y,0,      t0 + hs*0.8,     k[3]);
    stage(0, 4, k[0],A51, k[1],A52, k[2],A53, k[3],A54, y,0,      t0 + hs*(8.0/9), k[4]);
    stage(0, 5, k[0],A61, k[1],A62, k[2],A63, k[3],A64, k[4],A65, t0 + hs,         k[5]);
  }
  head_kernel<<<256, 256, 0, stream>>>(y, k[0], k[2], k[3], k[4], k[5],
      (float)(hs*B1), (float)(hs*B3), (float)(hs*B4), (float)(hs*B5), (float)(hs*B6),
      ogg, ogb, fcw, fcb, out);
}